// Round 5
// baseline (146.836 us; speedup 1.0000x reference)
//
#include <hip/hip_runtime.h>
#include <hip/hip_bf16.h>
#include <stdint.h>

#define EMBED 1024
#define NHEAD 16
#define DKD   64
#define BATCH 2
#define SEQ   2048
#define MROWS (BATCH*SEQ)   // 4096

typedef __attribute__((ext_vector_type(8)))  short bf16x8;
typedef __attribute__((ext_vector_type(4)))  float f32x4;
typedef __attribute__((ext_vector_type(16))) float f32x16;
typedef unsigned short u16;
typedef unsigned int   u32;
typedef __attribute__((ext_vector_type(4))) u32 u32x4;

__device__ inline u16 f2bf(float f) {
  return __builtin_bit_cast(u16, __float2bfloat16(f));  // single v_cvt, RNE
}

__device__ inline u32 cvtpk(float lo, float hi) {   // lo->bits[15:0], hi->bits[31:16]
  u32 r;
  asm("v_cvt_pk_bf16_f32 %0, %1, %2" : "=v"(r) : "v"(lo), "v"(hi));
  return r;
}

// X' = (h0: X_h0, h1: Y_h0) ; Y' = (h0: X_h1, h1: Y_h1)   [vdst.row1 <-> vsrc.row0]
__device__ inline void plswap(u32& x, u32& y) {
  asm volatile("v_permlane32_swap_b32 %0, %1" : "+v"(x), "+v"(y));
}

__device__ inline void gload_lds16(const u16* g, u16* l) {
  __builtin_amdgcn_global_load_lds(
      (const __attribute__((address_space(1))) u32*)(const void*)g,
      (__attribute__((address_space(3))) u32*)(void*)l, 16, 0, 0);
}

// ---------------- fused cast fp32 -> bf16 (all 7 tensors, 1 launch) --------
__global__ __launch_bounds__(256) void cast_all(
    const float* __restrict__ s0, const float* __restrict__ s1,
    const float* __restrict__ s2, const float* __restrict__ s3,
    const float* __restrict__ s4, const float* __restrict__ s5,
    const float* __restrict__ s6,
    u16* __restrict__ d0, u16* __restrict__ d1, u16* __restrict__ d2,
    u16* __restrict__ d3, u16* __restrict__ d4, u16* __restrict__ d5,
    u16* __restrict__ d6) {
  const int y = blockIdx.y;
  const float* s; u16* d; int n4;
  switch (y) {
    case 0: s = s0; d = d0; n4 = MROWS*EMBED/4; break;
    case 1: s = s1; d = d1; n4 = MROWS*EMBED/4; break;
    case 2: s = s2; d = d2; n4 = MROWS*EMBED/4; break;
    case 3: s = s3; d = d3; n4 = EMBED*EMBED/4; break;
    case 4: s = s4; d = d4; n4 = EMBED*EMBED/4; break;
    case 5: s = s5; d = d5; n4 = EMBED*EMBED/4; break;
    default: s = s6; d = d6; n4 = EMBED*EMBED/4; break;
  }
  int i = blockIdx.x * 256 + threadIdx.x;
  int stride = gridDim.x * 256;
  for (int idx = i; idx < n4; idx += stride) {
    float4 f = ((const float4*)s)[idx];
    ushort4 o;
    o.x = f2bf(f.x); o.y = f2bf(f.y); o.z = f2bf(f.z); o.w = f2bf(f.w);
    ((ushort4*)d)[idx] = o;
  }
}

// ---------------- fused QKV projection GEMM (B^T), BM=128, grid.z selects --
__global__ __launch_bounds__(256)
void gemm_qkv(const u16* __restrict__ A0, const u16* __restrict__ A1,
              const u16* __restrict__ A2, const u16* __restrict__ B0,
              const u16* __restrict__ B1, const u16* __restrict__ B2,
              u16* __restrict__ C0, u16* __restrict__ C1, u16* __restrict__ C2) {
  constexpr int K = EMBED;
  __shared__ u16 As[128 * 32];
  __shared__ u16 Bs[128 * 32];
  const int z = blockIdx.z;
  const u16* A = (z == 0) ? A0 : (z == 1) ? A1 : A2;
  const u16* B = (z == 0) ? B0 : (z == 1) ? B1 : B2;
  u16* C       = (z == 0) ? C0 : (z == 1) ? C1 : C2;

  const int t = threadIdx.x;
  const int w = t >> 6, l = t & 63;
  const int lr = l & 15, lg = l >> 4;
  const int m0 = blockIdx.x * 128;
  const int n0 = blockIdx.y * 128;
  const int wr = (w >> 1) * 64, wc = (w & 1) * 64;

  f32x4 acc[4][4] = {};

  const int srow = t >> 2;
  const int scol = (t & 3) * 8;
  const u16* Ag = A + (size_t)(m0 + srow) * K + scol;
  const u16* Bg = B + (size_t)(n0 + srow) * K + scol;
  u16* AsW = As + w * 512;
  u16* BsW = Bs + w * 512;
  const size_t rowstep = (size_t)64 * K;

  for (int k0 = 0; k0 < K; k0 += 32) {
    gload_lds16(Ag + k0,           AsW);
    gload_lds16(Ag + k0 + rowstep, AsW + 64 * 32);
    gload_lds16(Bg + k0,           BsW);
    gload_lds16(Bg + k0 + rowstep, BsW + 64 * 32);
    __syncthreads();
    bf16x8 a[4], b[4];
#pragma unroll
    for (int r = 0; r < 4; r++)
      a[r] = *(const bf16x8*)(As + (wr + r * 16 + lr) * 32 + 8 * lg);
#pragma unroll
    for (int c = 0; c < 4; c++)
      b[c] = *(const bf16x8*)(Bs + (wc + c * 16 + lr) * 32 + 8 * lg);
#pragma unroll
    for (int r = 0; r < 4; r++)
#pragma unroll
      for (int c = 0; c < 4; c++)
        acc[r][c] = __builtin_amdgcn_mfma_f32_16x16x32_bf16(a[r], b[c], acc[r][c], 0, 0, 0);
    __syncthreads();
  }

#pragma unroll
  for (int r = 0; r < 4; r++)
#pragma unroll
    for (int c = 0; c < 4; c++)
#pragma unroll
      for (int j = 0; j < 4; j++) {
        int m = m0 + wr + r * 16 + lg * 4 + j;
        int n = n0 + wc + c * 16 + lr;
        int b_ = m >> 11, s_ = m & 2047;
        int h_ = n >> 6,  d_ = n & 63;
        u16 vv = f2bf(acc[r][c][j]);
        if (z == 2)
          C[((size_t)(b_ * NHEAD + h_) * DKD + d_) * SEQ + s_] = vv;   // V^T
        else
          C[(((size_t)(b_ * NHEAD + h_) * SEQ + s_) << 6) + d_] = vv;  // heads
      }
}

// ---------------- output GEMM (B^T), BM=64 x BN=128, fp32 out -------------
__global__ __launch_bounds__(256)
void gemm_out(const u16* __restrict__ A, const u16* __restrict__ B,
              float* __restrict__ C) {
  constexpr int K = EMBED, N = EMBED;
  __shared__ u16 As[64 * 32];
  __shared__ u16 Bs[128 * 32];
  const int t = threadIdx.x;
  const int w = t >> 6, l = t & 63;
  const int lr = l & 15, lg = l >> 4;
  const int m0 = blockIdx.x * 64;
  const int n0 = blockIdx.y * 128;
  const int wr = (w >> 1) * 32, wc = (w & 1) * 64;

  f32x4 acc[2][4] = {};

  const int srow = t >> 2;
  const int scol = (t & 3) * 8;
  const u16* Ag = A + (size_t)(m0 + srow) * K + scol;
  const u16* Bg = B + (size_t)(n0 + srow) * K + scol;
  u16* AsW = As + w * 512;
  u16* BsW = Bs + w * 512;
  const size_t rowstep = (size_t)64 * K;

  for (int k0 = 0; k0 < K; k0 += 32) {
    gload_lds16(Ag + k0,           AsW);
    gload_lds16(Bg + k0,           BsW);
    gload_lds16(Bg + k0 + rowstep, BsW + 64 * 32);
    __syncthreads();
    bf16x8 a[2], b[4];
#pragma unroll
    for (int r = 0; r < 2; r++)
      a[r] = *(const bf16x8*)(As + (wr + r * 16 + lr) * 32 + 8 * lg);
#pragma unroll
    for (int c = 0; c < 4; c++)
      b[c] = *(const bf16x8*)(Bs + (wc + c * 16 + lr) * 32 + 8 * lg);
#pragma unroll
    for (int r = 0; r < 2; r++)
#pragma unroll
      for (int c = 0; c < 4; c++)
        acc[r][c] = __builtin_amdgcn_mfma_f32_16x16x32_bf16(a[r], b[c], acc[r][c], 0, 0, 0);
    __syncthreads();
  }

#pragma unroll
  for (int r = 0; r < 2; r++)
#pragma unroll
    for (int c = 0; c < 4; c++)
#pragma unroll
      for (int j = 0; j < 4; j++) {
        int m = m0 + wr + r * 16 + lg * 4 + j;
        int n = n0 + wc + c * 16 + lr;
        C[(size_t)m * N + n] = acc[r][c][j];
      }
}

// ---------------- flash attention v5: split-KV 8-wave blocks ---------------
// Waves 0-3 scan kv tiles 0..15, waves 4-7 scan 16..31, same 128 q rows.
// Swapped QK^T / swapped PV / in-register P-repack as v4. In-block combine.
// Qh,Kh: [B,H,S,DK] bf16; Vt: [B,H,DK,S] bf16; Xo: [B,S,E] bf16
__global__ __launch_bounds__(512, 4)
void attn_kernel(const u16* __restrict__ Qh, const u16* __restrict__ Kh,
                 const u16* __restrict__ Vt, u16* __restrict__ Xo) {
  __shared__ u16 KV[2][2][8192];   // [kvhalf][dbuf]: K[64kv][64d] | V^T[64d][64kv]
  const int t = threadIdx.x, w = t >> 6, l = t & 63;
  const int q32 = l & 31, h = l >> 5;
  const int hv = w >> 2, wq = w & 3;        // kv-half, q-subtile
  // XCD-clustered decode: XCD k owns bh in {4k..4k+3}
  const int xcd = blockIdx.x & 7;
  const int li  = blockIdx.x >> 3;          // 0..63
  const int bh  = xcd * 4 + (li >> 4);
  const int qblk = li & 15;
  const int b_ = bh >> 4, h_ = bh & 15;
  const size_t base = (size_t)bh * SEQ * DKD;
  const u16* Kb = Kh + base;
  const u16* Vb = Vt + base;                // [DK][SEQ]
  constexpr int NT2 = SEQ / 64 / 2;         // 16 tiles per half
  constexpr float C2 = 0.18033688f;         // 0.125 * log2(e)
  constexpr float THR = 44.0f;              // raw-domain defer-max bound (~2^8)

  // Q fragments (B-operand, 32x32x16): lane holds Q[q=q32][d=16ks+8h+e]
  const int qrow = qblk * 128 + wq * 32 + q32;
  bf16x8 qf[4];
#pragma unroll
  for (int ks = 0; ks < 4; ks++)
    qf[ks] = *(const bf16x8*)(Qh + base + (size_t)qrow * DKD + ks * 16 + h * 8);

  f32x16 acc[2] = {};                       // O^T: lane q=q32, d=(r&3)+8(r>>2)+4h+32dc
  float m2 = -1e30f, lsum = 0.f;

  // LDS tile swizzle: slot s at row R holds source col s ^ key(R),
  // key(R) = (R&7) ^ (R>>3)  (full 3-bit mix; rows r,r+8,r+16,r+24 disjoint)
  auto stage = [&](int buf, int kt) {
    u16* kd = &KV[hv][buf][0];
    u16* vd = &KV[hv][buf][4096];
    const int rb = wq * 8 + (l >> 3);
    const int ktile = hv * NT2 + kt;
#pragma unroll
    for (int ch = 0; ch < 2; ch++) {
      int row = ch * 32 + rb;
      int sg = (l & 7) ^ (l >> 3) ^ (ch * 4 + wq);
      gload_lds16(Kb + (size_t)(ktile * 64 + row) * DKD + sg * 8,
                  kd + (ch * 32 + wq * 8) * 64);
      gload_lds16(Vb + (size_t)row * SEQ + ktile * 64 + sg * 8,
                  vd + (ch * 32 + wq * 8) * 64);
    }
  };

  auto compute = [&](int buf) {
    const u16* kd = &KV[hv][buf][0];
    const u16* vd = &KV[hv][buf][4096];
    // ---- QK^T swapped: s[c] = S^T[kv=c*32+(r&3)+8(r>>2)+4h][q=q32]
    f32x16 s[2] = {};
#pragma unroll
    for (int c = 0; c < 2; c++) {
      int row = c * 32 + q32;
      int key = (q32 & 7) ^ (c * 4 + (q32 >> 3));
#pragma unroll
      for (int ks = 0; ks < 4; ks++) {
        bf16x8 kf = *(const bf16x8*)(kd + row * 64 + (((2 * ks + h) ^ key) * 8));
        s[c] = __builtin_amdgcn_mfma_f32_32x32x16_bf16(kf, qf[ks], s[c], 0, 0, 0);
      }
    }
    // ---- V fragments early (hide ds latency under softmax VALU)
    bf16x8 vf[2][4];
#pragma unroll
    for (int dc = 0; dc < 2; dc++) {
      int row = dc * 32 + q32;
      int key = (q32 & 7) ^ (dc * 4 + (q32 >> 3));
#pragma unroll
      for (int tile = 0; tile < 4; tile++)
        vf[dc][tile] = *(const bf16x8*)(vd + row * 64 + (((2 * tile + h) ^ key) * 8));
    }
    // ---- per-lane max over this tile's 32 scores (balanced tree)
    float mx[16];
#pragma unroll
    for (int r = 0; r < 16; r++) mx[r] = fmaxf(s[0][r], s[1][r]);
#pragma unroll
    for (int off = 8; off >= 1; off >>= 1)
#pragma unroll
      for (int r = 0; r < off; r++) mx[r] = fmaxf(mx[r], mx[r + off]);
    float pm = mx[0];
    if (__any(pm > m2 + THR)) {             // defer-max trigger (rare)
      float pmo = __shfl_xor(pm, 32, 64);   // row max needs both h halves
      float mn = fmaxf(m2, fmaxf(pm, pmo));
      float al = __builtin_amdgcn_exp2f((m2 - mn) * C2);
      lsum *= al;
#pragma unroll
      for (int dc = 0; dc < 2; dc++)
#pragma unroll
        for (int r = 0; r < 16; r++) acc[dc][r] *= al;
      m2 = mn;
    }
    // ---- P = exp2((s-m)*C2); balanced sum; pack + permlane into B-frags
    const float nm = -m2 * C2;
    bf16x8 pfrag[4];
    float ls = 0.f;
#pragma unroll
    for (int c = 0; c < 2; c++) {
      float p[16];
#pragma unroll
      for (int r = 0; r < 16; r++)
        p[r] = __builtin_amdgcn_exp2f(__builtin_fmaf(s[c][r], C2, nm));
      float s0 = ((p[0] + p[1]) + (p[2] + p[3])) + ((p[4] + p[5]) + (p[6] + p[7]));
      float s1 = ((p[8] + p[9]) + (p[10] + p[11])) + ((p[12] + p[13]) + (p[14] + p[15]));
      ls += s0 + s1;
      u32 Pk[8];
#pragma unroll
      for (int i = 0; i < 8; i++) Pk[i] = cvtpk(p[2 * i], p[2 * i + 1]);
      plswap(Pk[0], Pk[2]); plswap(Pk[1], Pk[3]);
      plswap(Pk[4], Pk[6]); plswap(Pk[5], Pk[7]);
      pfrag[2 * c]     = __builtin_bit_cast(bf16x8, (u32x4){Pk[0], Pk[1], Pk[2], Pk[3]});
      pfrag[2 * c + 1] = __builtin_bit_cast(bf16x8, (u32x4){Pk[4], Pk[5], Pk[6], Pk[7]});
    }
    lsum += ls;
    // ---- PV swapped: acc[dc] += V^T-frag x P-frag  (D = O^T)
#pragma unroll
    for (int tile = 0; tile < 4; tile++)
#pragma unroll
      for (int dc = 0; dc < 2; dc++)
        acc[dc] = __builtin_amdgcn_mfma_f32_32x32x16_bf16(vf[dc][tile], pfrag[tile], acc[dc], 0, 0, 0);
  };

  stage(0, 0);
  __syncthreads();
  int cur = 0;
  for (int kt = 0; kt < NT2; kt++) {
    if (kt + 1 < NT2) stage(cur ^ 1, kt + 1);
    compute(cur);
    __syncthreads();
    cur ^= 1;
  }

  // ---- in-block split-KV combine: upper half dumps partials, lower merges
  float* shf = (float*)&KV[0][0][0];        // reuse (post-barrier), 36.9KB used
  if (hv == 1) {
    float* dst = shf + (size_t)(wq * 64 + l) * 36;
#pragma unroll
    for (int dc = 0; dc < 2; dc++)
#pragma unroll
      for (int k4 = 0; k4 < 4; k4++) {
        float4 v4o = {acc[dc][4 * k4 + 0], acc[dc][4 * k4 + 1],
                      acc[dc][4 * k4 + 2], acc[dc][4 * k4 + 3]};
        *(float4*)(dst + dc * 16 + k4 * 4) = v4o;
      }
    dst[32] = m2;
    dst[33] = lsum;
  }
  __syncthreads();
  if (hv == 0) {
    const float* src = shf + (size_t)(wq * 64 + l) * 36;
    float m2b = src[32], lsb = src[33];
    float mN = fmaxf(m2, m2b);
    float a0 = __builtin_amdgcn_exp2f((m2 - mN) * C2);
    float a1 = __builtin_amdgcn_exp2f((m2b - mN) * C2);
    float lv = lsum * a0 + lsb * a1;
    lv += __shfl_xor(lv, 32, 64);
    float inv = 1.0f / lv;
    u16* orow = Xo + ((size_t)b_ * SEQ + qrow) * EMBED + h_ * DKD;
#pragma unroll
    for (int dc = 0; dc < 2; dc++)
#pragma unroll
      for (int k4 = 0; k4 < 4; k4++) {
        float4 ob = *(const float4*)(src + dc * 16 + k4 * 4);
        float o0 = (acc[dc][4 * k4 + 0] * a0 + ob.x * a1) * inv;
        float o1 = (acc[dc][4 * k4 + 1] * a0 + ob.y * a1) * inv;
        float o2 = (acc[dc][4 * k4 + 2] * a0 + ob.z * a1) * inv;
        float o3 = (acc[dc][4 * k4 + 3] * a0 + ob.w * a1) * inv;
        uint2 pk; pk.x = cvtpk(o0, o1); pk.y = cvtpk(o2, o3);
        *(uint2*)(orow + dc * 32 + k4 * 8 + h * 4) = pk;
      }
  }
}

extern "C" void kernel_launch(void* const* d_in, const int* in_sizes, int n_in,
                              void* d_out, int out_size, void* d_ws, size_t ws_size,
                              hipStream_t stream) {
  const float* q  = (const float*)d_in[0];
  const float* k  = (const float*)d_in[1];
  const float* v  = (const float*)d_in[2];
  const float* Wq = (const float*)d_in[3];
  const float* Wk = (const float*)d_in[4];
  const float* Wv = (const float*)d_in[5];
  const float* Wo = (const float*)d_in[6];

  char* ws = (char*)d_ws;
  const size_t SZ_X = (size_t)MROWS * EMBED * 2;   // 8 MiB
  const size_t SZ_W = (size_t)EMBED * EMBED * 2;   // 2 MiB
  u16* qbf  = (u16*)(ws);
  u16* kbf  = (u16*)(ws + SZ_X);
  u16* vbf  = (u16*)(ws + 2 * SZ_X);
  u16* wqb  = (u16*)(ws + 3 * SZ_X);
  u16* wkb  = (u16*)(ws + 3 * SZ_X + SZ_W);
  u16* wvb  = (u16*)(ws + 3 * SZ_X + 2 * SZ_W);
  u16* wob  = (u16*)(ws + 3 * SZ_X + 3 * SZ_W);
  u16* Qh   = (u16*)(ws + 3 * SZ_X + 4 * SZ_W);
  u16* Kh   = (u16*)(ws + 4 * SZ_X + 4 * SZ_W);
  u16* Vt   = (u16*)(ws + 5 * SZ_X + 4 * SZ_W);
  u16* Xcat = (u16*)(ws + 6 * SZ_X + 4 * SZ_W);    // total 64 MiB

  cast_all<<<dim3(1024, 7), 256, 0, stream>>>(q, k, v, Wq, Wk, Wv, Wo,
                                              qbf, kbf, vbf, wqb, wkb, wvb, wob);

  gemm_qkv<<<dim3(MROWS / 128, EMBED / 128, 3), 256, 0, stream>>>(
      qbf, kbf, vbf, wqb, wkb, wvb, Qh, Kh, Vt);

  attn_kernel<<<512, 512, 0, stream>>>(Qh, Kh, Vt, Xcat);

  gemm_out<<<dim3(MROWS / 64, EMBED / 128), 256, 0, stream>>>(Xcat, wob, (float*)d_out);
}

// Round 8
// 137.307 us; speedup vs baseline: 1.0694x; 1.0694x over previous
//
#include <hip/hip_runtime.h>
#include <hip/hip_bf16.h>
#include <stdint.h>

#define EMBED 1024
#define NHEAD 16
#define DKD   64
#define BATCH 2
#define SEQ   2048
#define MROWS (BATCH*SEQ)   // 4096

typedef __attribute__((ext_vector_type(8)))  short bf16x8;
typedef __attribute__((ext_vector_type(4)))  float f32x4;
typedef __attribute__((ext_vector_type(16))) float f32x16;
typedef unsigned short u16;
typedef unsigned int   u32;
typedef __attribute__((ext_vector_type(4))) u32 u32x4;

__device__ inline u16 f2bf(float f) {
  return __builtin_bit_cast(u16, __float2bfloat16(f));  // single v_cvt, RNE
}
__device__ inline float bf2f(u16 x) {
  u32 u = ((u32)x) << 16;
  return __builtin_bit_cast(float, u);
}

__device__ inline u32 cvtpk(float lo, float hi) {   // lo->bits[15:0], hi->bits[31:16]
  u32 r;
  asm("v_cvt_pk_bf16_f32 %0, %1, %2" : "=v"(r) : "v"(lo), "v"(hi));
  return r;
}

// X' = (h0: X_h0, h1: Y_h0) ; Y' = (h0: X_h1, h1: Y_h1)   [vdst.row1 <-> vsrc.row0]
__device__ inline void plswap(u32& x, u32& y) {
  asm volatile("v_permlane32_swap_b32 %0, %1" : "+v"(x), "+v"(y));
}

__device__ inline void gload_lds16(const u16* g, u16* l) {
  __builtin_amdgcn_global_load_lds(
      (const __attribute__((address_space(1))) u32*)(const void*)g,
      (__attribute__((address_space(3))) u32*)(void*)l, 16, 0, 0);
}

// ---------------- fused cast fp32 -> bf16 (all 7 tensors, 1 launch) --------
__global__ __launch_bounds__(256) void cast_all(
    const float* __restrict__ s0, const float* __restrict__ s1,
    const float* __restrict__ s2, const float* __restrict__ s3,
    const float* __restrict__ s4, const float* __restrict__ s5,
    const float* __restrict__ s6,
    u16* __restrict__ d0, u16* __restrict__ d1, u16* __restrict__ d2,
    u16* __restrict__ d3, u16* __restrict__ d4, u16* __restrict__ d5,
    u16* __restrict__ d6) {
  const int y = blockIdx.y;
  const float* s; u16* d; int n4;
  switch (y) {
    case 0: s = s0; d = d0; n4 = MROWS*EMBED/4; break;
    case 1: s = s1; d = d1; n4 = MROWS*EMBED/4; break;
    case 2: s = s2; d = d2; n4 = MROWS*EMBED/4; break;
    case 3: s = s3; d = d3; n4 = EMBED*EMBED/4; break;
    case 4: s = s4; d = d4; n4 = EMBED*EMBED/4; break;
    case 5: s = s5; d = d5; n4 = EMBED*EMBED/4; break;
    default: s = s6; d = d6; n4 = EMBED*EMBED/4; break;
  }
  int i = blockIdx.x * 256 + threadIdx.x;
  int stride = gridDim.x * 256;
  for (int idx = i; idx < n4; idx += stride) {
    float4 f = ((const float4*)s)[idx];
    ushort4 o;
    o.x = f2bf(f.x); o.y = f2bf(f.y); o.z = f2bf(f.z); o.w = f2bf(f.w);
    ((ushort4*)d)[idx] = o;
  }
}

// ---------------- fused QKV projection GEMM (B^T), BM=128, grid.z selects --
__global__ __launch_bounds__(256)
void gemm_qkv(const u16* __restrict__ A0, const u16* __restrict__ A1,
              const u16* __restrict__ A2, const u16* __restrict__ B0,
              const u16* __restrict__ B1, const u16* __restrict__ B2,
              u16* __restrict__ C0, u16* __restrict__ C1, u16* __restrict__ C2) {
  constexpr int K = EMBED;
  __shared__ u16 As[128 * 32];
  __shared__ u16 Bs[128 * 32];
  const int z = blockIdx.z;
  const u16* A = (z == 0) ? A0 : (z == 1) ? A1 : A2;
  const u16* B = (z == 0) ? B0 : (z == 1) ? B1 : B2;
  u16* C       = (z == 0) ? C0 : (z == 1) ? C1 : C2;

  const int t = threadIdx.x;
  const int w = t >> 6, l = t & 63;
  const int lr = l & 15, lg = l >> 4;
  const int m0 = blockIdx.x * 128;
  const int n0 = blockIdx.y * 128;
  const int wr = (w >> 1) * 64, wc = (w & 1) * 64;

  f32x4 acc[4][4] = {};

  const int srow = t >> 2;
  const int scol = (t & 3) * 8;
  const u16* Ag = A + (size_t)(m0 + srow) * K + scol;
  const u16* Bg = B + (size_t)(n0 + srow) * K + scol;
  u16* AsW = As + w * 512;
  u16* BsW = Bs + w * 512;
  const size_t rowstep = (size_t)64 * K;

  for (int k0 = 0; k0 < K; k0 += 32) {
    gload_lds16(Ag + k0,           AsW);
    gload_lds16(Ag + k0 + rowstep, AsW + 64 * 32);
    gload_lds16(Bg + k0,           BsW);
    gload_lds16(Bg + k0 + rowstep, BsW + 64 * 32);
    __syncthreads();
    bf16x8 a[4], b[4];
#pragma unroll
    for (int r = 0; r < 4; r++)
      a[r] = *(const bf16x8*)(As + (wr + r * 16 + lr) * 32 + 8 * lg);
#pragma unroll
    for (int c = 0; c < 4; c++)
      b[c] = *(const bf16x8*)(Bs + (wc + c * 16 + lr) * 32 + 8 * lg);
#pragma unroll
    for (int r = 0; r < 4; r++)
#pragma unroll
      for (int c = 0; c < 4; c++)
        acc[r][c] = __builtin_amdgcn_mfma_f32_16x16x32_bf16(a[r], b[c], acc[r][c], 0, 0, 0);
    __syncthreads();
  }

#pragma unroll
  for (int r = 0; r < 4; r++)
#pragma unroll
    for (int c = 0; c < 4; c++)
#pragma unroll
      for (int j = 0; j < 4; j++) {
        int m = m0 + wr + r * 16 + lg * 4 + j;
        int n = n0 + wc + c * 16 + lr;
        int b_ = m >> 11, s_ = m & 2047;
        int h_ = n >> 6,  d_ = n & 63;
        u16 vv = f2bf(acc[r][c][j]);
        if (z == 2)
          C[((size_t)(b_ * NHEAD + h_) * DKD + d_) * SEQ + s_] = vv;   // V^T
        else
          C[(((size_t)(b_ * NHEAD + h_) * SEQ + s_) << 6) + d_] = vv;  // heads
      }
}

// ---------------- output GEMM (B^T), BM=64 x BN=128, fp32 out -------------
__global__ __launch_bounds__(256)
void gemm_out(const u16* __restrict__ A, const u16* __restrict__ B,
              float* __restrict__ C) {
  constexpr int K = EMBED, N = EMBED;
  __shared__ u16 As[64 * 32];
  __shared__ u16 Bs[128 * 32];
  const int t = threadIdx.x;
  const int w = t >> 6, l = t & 63;
  const int lr = l & 15, lg = l >> 4;
  const int m0 = blockIdx.x * 64;
  const int n0 = blockIdx.y * 128;
  const int wr = (w >> 1) * 32, wc = (w & 1) * 64;

  f32x4 acc[2][4] = {};

  const int srow = t >> 2;
  const int scol = (t & 3) * 8;
  const u16* Ag = A + (size_t)(m0 + srow) * K + scol;
  const u16* Bg = B + (size_t)(n0 + srow) * K + scol;
  u16* AsW = As + w * 512;
  u16* BsW = Bs + w * 512;
  const size_t rowstep = (size_t)64 * K;

  for (int k0 = 0; k0 < K; k0 += 32) {
    gload_lds16(Ag + k0,           AsW);
    gload_lds16(Bg + k0,           BsW);
    gload_lds16(Bg + k0 + rowstep, BsW + 64 * 32);
    __syncthreads();
    bf16x8 a[2], b[4];
#pragma unroll
    for (int r = 0; r < 2; r++)
      a[r] = *(const bf16x8*)(As + (wr + r * 16 + lr) * 32 + 8 * lg);
#pragma unroll
    for (int c = 0; c < 4; c++)
      b[c] = *(const bf16x8*)(Bs + (wc + c * 16 + lr) * 32 + 8 * lg);
#pragma unroll
    for (int r = 0; r < 2; r++)
#pragma unroll
      for (int c = 0; c < 4; c++)
        acc[r][c] = __builtin_amdgcn_mfma_f32_16x16x32_bf16(a[r], b[c], acc[r][c], 0, 0, 0);
    __syncthreads();
  }

#pragma unroll
  for (int r = 0; r < 2; r++)
#pragma unroll
    for (int c = 0; c < 4; c++)
#pragma unroll
      for (int j = 0; j < 4; j++) {
        int m = m0 + wr + r * 16 + lg * 4 + j;
        int n = n0 + wc + c * 16 + lr;
        C[(size_t)m * N + n] = acc[r][c][j];
      }
}

// ---------------- flash attention v8: block-level split-KV -----------------
// v4's verified compute path verbatim; blockIdx.y = kv-half (16 tiles each).
// Epilogue NORMALIZES (O_half = acc/l_half) before bf16 partial store, so
// bf16 rounding applies at O-magnitude, not unnormalized-acc magnitude.
// Qh,Kh: [B,H,S,DK] bf16; Vt: [B,H,DK,S] bf16
__global__ __launch_bounds__(256, 4)
void attn_part(const u16* __restrict__ Qh, const u16* __restrict__ Kh,
               const u16* __restrict__ Vt, u16* __restrict__ Opart,
               float* __restrict__ MLpart) {
  __shared__ u16 KV[2][8192];      // per buf: K[64 kv][64 d] | V^T[64 d][64 kv], XOR-swizzled
  const int t = threadIdx.x, w = t >> 6, l = t & 63;
  const int q32 = l & 31, h = l >> 5;
  // XCD-clustered decode: XCD k owns bh in {4k..4k+3}
  const int xcd = blockIdx.x & 7;
  const int li  = blockIdx.x >> 3;          // 0..63
  const int bh  = xcd * 4 + (li >> 4);
  const int qblk = li & 15;
  const int hv = blockIdx.y;                // kv half: tiles [hv*16, hv*16+16)
  const size_t base = (size_t)bh * SEQ * DKD;
  const u16* Kb = Kh + base;
  const u16* Vb = Vt + base;                // [DK][SEQ]
  constexpr int NT2 = SEQ / 64 / 2;         // 16 tiles per half
  constexpr float C2 = 0.18033688f;         // 0.125 * log2(e)
  constexpr float THR = 44.0f;              // raw-domain defer-max bound (~2^8)

  // Q fragments (B-operand, 32x32x16): lane holds Q[q=q32][d=16ks+8h+e]
  const int qrow = qblk * 128 + w * 32 + q32;
  bf16x8 qf[4];
#pragma unroll
  for (int ks = 0; ks < 4; ks++)
    qf[ks] = *(const bf16x8*)(Qh + base + (size_t)qrow * DKD + ks * 16 + h * 8);

  f32x16 acc[2] = {};                       // O^T: lane q=q32, d=(r&3)+8(r>>2)+4h+32dc
  float m2 = -1e30f, lsum = 0.f;

  auto stage = [&](int buf, int kt) {
    u16* kd = &KV[buf][0];
    u16* vd = &KV[buf][4096];
    const int rb = w * 8 + (l >> 3);        // wave-local row band
    const int sg = (l & 7) ^ (l >> 3);      // pre-swizzled source slot
    const int ktile = hv * NT2 + kt;
#pragma unroll
    for (int ch = 0; ch < 2; ch++) {
      int row = ch * 32 + rb;
      gload_lds16(Kb + (size_t)(ktile * 64 + row) * DKD + sg * 8,
                  kd + (ch * 32 + w * 8) * 64);
      gload_lds16(Vb + (size_t)row * SEQ + ktile * 64 + sg * 8,
                  vd + (ch * 32 + w * 8) * 64);
    }
  };

  auto compute = [&](int buf) {
    const u16* kd = &KV[buf][0];
    const u16* vd = &KV[buf][4096];
    // ---- QK^T swapped: s[c] = S^T[kv=c*32+(r&3)+8(r>>2)+4h][q=q32]
    f32x16 s[2] = {};
#pragma unroll
    for (int c = 0; c < 2; c++) {
      int row = c * 32 + q32;
#pragma unroll
      for (int ks = 0; ks < 4; ks++) {
        bf16x8 kf = *(const bf16x8*)(kd + row * 64 + (((2 * ks + h) ^ (row & 7)) * 8));
        s[c] = __builtin_amdgcn_mfma_f32_32x32x16_bf16(kf, qf[ks], s[c], 0, 0, 0);
      }
    }
    // ---- V fragments early (hide ds latency under softmax VALU)
    bf16x8 vf[2][4];
#pragma unroll
    for (int dc = 0; dc < 2; dc++) {
      int row = dc * 32 + q32;
#pragma unroll
      for (int tile = 0; tile < 4; tile++)
        vf[dc][tile] = *(const bf16x8*)(vd + row * 64 + (((2 * tile + h) ^ (row & 7)) * 8));
    }
    // ---- per-lane max over this tile's 32 scores (raw domain)
    float pm = s[0][0];
#pragma unroll
    for (int r = 1; r < 16; r++) pm = fmaxf(pm, s[0][r]);
#pragma unroll
    for (int r = 0; r < 16; r++) pm = fmaxf(pm, s[1][r]);
    if (__any(pm > m2 + THR)) {             // defer-max trigger (rare)
      float pmo = __shfl_xor(pm, 32, 64);   // true row max needs both halves
      float mn = fmaxf(m2, fmaxf(pm, pmo));
      float al = __builtin_amdgcn_exp2f((m2 - mn) * C2);
      lsum *= al;
#pragma unroll
      for (int dc = 0; dc < 2; dc++)
#pragma unroll
        for (int r = 0; r < 16; r++) acc[dc][r] *= al;
      m2 = mn;
    }
    // ---- P = exp2((s-m)*C2); pack + permlane-swap into PV B-fragments
    const float nm = -m2 * C2;
    bf16x8 pfrag[4];
    float ls = 0.f;
#pragma unroll
    for (int c = 0; c < 2; c++) {
      float p[16];
#pragma unroll
      for (int r = 0; r < 16; r++) {
        p[r] = __builtin_amdgcn_exp2f(__builtin_fmaf(s[c][r], C2, nm));
        ls += p[r];
      }
      u32 Pk[8];
#pragma unroll
      for (int i = 0; i < 8; i++) Pk[i] = cvtpk(p[2 * i], p[2 * i + 1]);
      plswap(Pk[0], Pk[2]); plswap(Pk[1], Pk[3]);
      plswap(Pk[4], Pk[6]); plswap(Pk[5], Pk[7]);
      pfrag[2 * c]     = __builtin_bit_cast(bf16x8, (u32x4){Pk[0], Pk[1], Pk[2], Pk[3]});
      pfrag[2 * c + 1] = __builtin_bit_cast(bf16x8, (u32x4){Pk[4], Pk[5], Pk[6], Pk[7]});
    }
    lsum += ls;
    // ---- PV swapped: acc[dc] += V^T-frag x P-frag  (D = O^T)
#pragma unroll
    for (int tile = 0; tile < 4; tile++)
#pragma unroll
      for (int dc = 0; dc < 2; dc++)
        acc[dc] = __builtin_amdgcn_mfma_f32_32x32x16_bf16(vf[dc][tile], pfrag[tile], acc[dc], 0, 0, 0);
  };

  stage(0, 0);
  __syncthreads();
  int cur = 0;
  for (int kt = 0; kt < NT2; kt++) {
    if (kt + 1 < NT2) stage(cur ^ 1, kt + 1);
    compute(cur);
    __syncthreads();
    cur ^= 1;
  }

  // ---- epilogue: normalize by this half's row sum, THEN write bf16 partials
  const float lpair = lsum + __shfl_xor(lsum, 32, 64);  // full row sum (this half)
  const float invl = 1.0f / lpair;
  const int entry = (bh * 16 + qblk) * 2 + hv;
  u16* op = Opart + (size_t)entry * (128 * 64) + (size_t)(w * 32 + q32) * 64;
#pragma unroll
  for (int dc = 0; dc < 2; dc++)
#pragma unroll
    for (int k4 = 0; k4 < 4; k4++) {
      uint2 pk;
      pk.x = cvtpk(acc[dc][4 * k4 + 0] * invl, acc[dc][4 * k4 + 1] * invl);
      pk.y = cvtpk(acc[dc][4 * k4 + 2] * invl, acc[dc][4 * k4 + 3] * invl);
      *(uint2*)(op + dc * 32 + k4 * 8 + h * 4) = pk;
    }
  if (h == 0) {
    float2 ml; ml.x = m2; ml.y = lpair;   // m2 identical across the h-pair
    *(float2*)(MLpart + (size_t)entry * 256 + (w * 32 + q32) * 2) = ml;
  }
}

// ---------------- split-KV combine: O = (w0*O0 + w1*O1), wi = li*ai/Σ ------
// One thread per (bh, q, d8-chunk). Writes merged heads into Xcat [B,S,E].
__global__ __launch_bounds__(256)
void attn_combine(const u16* __restrict__ Opart, const float* __restrict__ MLpart,
                  u16* __restrict__ Xo) {
  constexpr float C2 = 0.18033688f;
  int tid = blockIdx.x * 256 + threadIdx.x;
  int d8 = tid & 7;
  int qq = (tid >> 3) & 2047;
  int bh = tid >> 14;                       // 0..31
  int qblk = qq >> 7, qi = qq & 127;
  int e0 = (bh * 16 + qblk) * 2;
  float2 ml0 = *(const float2*)(MLpart + (size_t)e0 * 256 + qi * 2);
  float2 ml1 = *(const float2*)(MLpart + (size_t)(e0 + 1) * 256 + qi * 2);
  float mN = fmaxf(ml0.x, ml1.x);
  float w0 = __builtin_amdgcn_exp2f((ml0.x - mN) * C2) * ml0.y;
  float w1 = __builtin_amdgcn_exp2f((ml1.x - mN) * C2) * ml1.y;
  float inv = 1.0f / (w0 + w1);
  w0 *= inv; w1 *= inv;
  bf16x8 o0 = *(const bf16x8*)(Opart + (size_t)e0 * 8192 + qi * 64 + d8 * 8);
  bf16x8 o1 = *(const bf16x8*)(Opart + (size_t)(e0 + 1) * 8192 + qi * 64 + d8 * 8);
  u32 ow[4];
#pragma unroll
  for (int i = 0; i < 4; i++) {
    float f0 = bf2f((u16)o0[2 * i])     * w0 + bf2f((u16)o1[2 * i])     * w1;
    float f1 = bf2f((u16)o0[2 * i + 1]) * w0 + bf2f((u16)o1[2 * i + 1]) * w1;
    ow[i] = cvtpk(f0, f1);
  }
  int b_ = bh >> 4, h_ = bh & 15;
  *(u32x4*)(Xo + ((size_t)b_ * SEQ + qq) * EMBED + h_ * DKD + d8 * 8) =
      (u32x4){ow[0], ow[1], ow[2], ow[3]};
}

extern "C" void kernel_launch(void* const* d_in, const int* in_sizes, int n_in,
                              void* d_out, int out_size, void* d_ws, size_t ws_size,
                              hipStream_t stream) {
  const float* q  = (const float*)d_in[0];
  const float* k  = (const float*)d_in[1];
  const float* v  = (const float*)d_in[2];
  const float* Wq = (const float*)d_in[3];
  const float* Wk = (const float*)d_in[4];
  const float* Wv = (const float*)d_in[5];
  const float* Wo = (const float*)d_in[6];

  char* ws = (char*)d_ws;
  const size_t SZ_X = (size_t)MROWS * EMBED * 2;   // 8 MiB
  const size_t SZ_W = (size_t)EMBED * EMBED * 2;   // 2 MiB
  u16* qbf  = (u16*)(ws);
  u16* kbf  = (u16*)(ws + SZ_X);
  u16* vbf  = (u16*)(ws + 2 * SZ_X);
  u16* wqb  = (u16*)(ws + 3 * SZ_X);
  u16* wkb  = (u16*)(ws + 3 * SZ_X + SZ_W);
  u16* wvb  = (u16*)(ws + 3 * SZ_X + 2 * SZ_W);
  u16* wob  = (u16*)(ws + 3 * SZ_X + 3 * SZ_W);
  u16* Qh   = (u16*)(ws + 3 * SZ_X + 4 * SZ_W);
  u16* Kh   = (u16*)(ws + 4 * SZ_X + 4 * SZ_W);
  u16* Vt   = (u16*)(ws + 5 * SZ_X + 4 * SZ_W);
  u16* Xcat = (u16*)(ws + 6 * SZ_X + 4 * SZ_W);    // total 64 MiB

  // Partial buffers overlay qbf/kbf/vbf (dead after gemm_qkv):
  u16*   Opart  = (u16*)(ws);              // 1024 entries x 128x64 bf16 = 16 MiB
  float* MLpart = (float*)(ws + 2 * SZ_X); // 1024 entries x 128 x {m,l} = 1 MiB

  cast_all<<<dim3(1024, 7), 256, 0, stream>>>(q, k, v, Wq, Wk, Wv, Wo,
                                              qbf, kbf, vbf, wqb, wkb, wvb, wob);

  gemm_qkv<<<dim3(MROWS / 128, EMBED / 128, 3), 256, 0, stream>>>(
      qbf, kbf, vbf, wqb, wkb, wvb, Qh, Kh, Vt);

  attn_part<<<dim3(512, 2), 256, 0, stream>>>(Qh, Kh, Vt, Opart, MLpart);
  attn_combine<<<2048, 256, 0, stream>>>(Opart, MLpart, Xcat);

  gemm_out<<<dim3(MROWS / 64, EMBED / 128), 256, 0, stream>>>(Xcat, wob, (float*)d_out);
}

// Round 9
// 132.482 us; speedup vs baseline: 1.1084x; 1.0364x over previous
//
#include <hip/hip_runtime.h>
#include <hip/hip_bf16.h>
#include <stdint.h>

#define EMBED 1024
#define NHEAD 16
#define DKD   64
#define BATCH 2
#define SEQ   2048
#define MROWS (BATCH*SEQ)   // 4096

typedef __attribute__((ext_vector_type(8)))  short bf16x8;
typedef __attribute__((ext_vector_type(4)))  float f32x4;
typedef __attribute__((ext_vector_type(16))) float f32x16;
typedef unsigned short u16;
typedef unsigned int   u32;
typedef __attribute__((ext_vector_type(4))) u32 u32x4;

__device__ inline u16 f2bf(float f) {
  return __builtin_bit_cast(u16, __float2bfloat16(f));  // single v_cvt, RNE
}

__device__ inline u32 cvtpk(float lo, float hi) {   // lo->bits[15:0], hi->bits[31:16]
  u32 r;
  asm("v_cvt_pk_bf16_f32 %0, %1, %2" : "=v"(r) : "v"(lo), "v"(hi));
  return r;
}

// X' = (h0: X_h0, h1: Y_h0) ; Y' = (h0: X_h1, h1: Y_h1)   [vdst.row1 <-> vsrc.row0]
__device__ inline void plswap(u32& x, u32& y) {
  asm volatile("v_permlane32_swap_b32 %0, %1" : "+v"(x), "+v"(y));
}

__device__ inline void gload_lds16(const u16* g, u16* l) {
  __builtin_amdgcn_global_load_lds(
      (const __attribute__((address_space(1))) u32*)(const void*)g,
      (__attribute__((address_space(3))) u32*)(void*)l, 16, 0, 0);
}

// ---------------- fused cast fp32 -> bf16 (all 7 tensors, 1 launch) --------
__global__ __launch_bounds__(256) void cast_all(
    const float* __restrict__ s0, const float* __restrict__ s1,
    const float* __restrict__ s2, const float* __restrict__ s3,
    const float* __restrict__ s4, const float* __restrict__ s5,
    const float* __restrict__ s6,
    u16* __restrict__ d0, u16* __restrict__ d1, u16* __restrict__ d2,
    u16* __restrict__ d3, u16* __restrict__ d4, u16* __restrict__ d5,
    u16* __restrict__ d6) {
  const int y = blockIdx.y;
  const float* s; u16* d; int n4;
  switch (y) {
    case 0: s = s0; d = d0; n4 = MROWS*EMBED/4; break;
    case 1: s = s1; d = d1; n4 = MROWS*EMBED/4; break;
    case 2: s = s2; d = d2; n4 = MROWS*EMBED/4; break;
    case 3: s = s3; d = d3; n4 = EMBED*EMBED/4; break;
    case 4: s = s4; d = d4; n4 = EMBED*EMBED/4; break;
    case 5: s = s5; d = d5; n4 = EMBED*EMBED/4; break;
    default: s = s6; d = d6; n4 = EMBED*EMBED/4; break;
  }
  int i = blockIdx.x * 256 + threadIdx.x;
  int stride = gridDim.x * 256;
  for (int idx = i; idx < n4; idx += stride) {
    float4 f = ((const float4*)s)[idx];
    ushort4 o;
    o.x = f2bf(f.x); o.y = f2bf(f.y); o.z = f2bf(f.z); o.w = f2bf(f.w);
    ((ushort4*)d)[idx] = o;
  }
}

// ---------------- fused QKV projection GEMM (B^T), dbuf LDS ----------------
__global__ __launch_bounds__(256)
void gemm_qkv(const u16* __restrict__ A0, const u16* __restrict__ A1,
              const u16* __restrict__ A2, const u16* __restrict__ B0,
              const u16* __restrict__ B1, const u16* __restrict__ B2,
              u16* __restrict__ C0, u16* __restrict__ C1, u16* __restrict__ C2) {
  constexpr int K = EMBED;
  __shared__ u16 As[2][128 * 32];
  __shared__ u16 Bs[2][128 * 32];
  const int z = blockIdx.z;
  const u16* A = (z == 0) ? A0 : (z == 1) ? A1 : A2;
  const u16* B = (z == 0) ? B0 : (z == 1) ? B1 : B2;
  u16* C       = (z == 0) ? C0 : (z == 1) ? C1 : C2;

  const int t = threadIdx.x;
  const int w = t >> 6, l = t & 63;
  const int lr = l & 15, lg = l >> 4;
  const int m0 = blockIdx.x * 128;
  const int n0 = blockIdx.y * 128;
  const int wr = (w >> 1) * 64, wc = (w & 1) * 64;

  f32x4 acc[4][4] = {};

  const int srow = t >> 2;
  const int scol = (t & 3) * 8;
  const u16* Ag = A + (size_t)(m0 + srow) * K + scol;
  const u16* Bg = B + (size_t)(n0 + srow) * K + scol;
  const size_t rowstep = (size_t)64 * K;

  auto stage = [&](int buf, int k0) {
    gload_lds16(Ag + k0,           As[buf] + w * 512);
    gload_lds16(Ag + k0 + rowstep, As[buf] + 64 * 32 + w * 512);
    gload_lds16(Bg + k0,           Bs[buf] + w * 512);
    gload_lds16(Bg + k0 + rowstep, Bs[buf] + 64 * 32 + w * 512);
  };

  stage(0, 0);
  __syncthreads();
  int cur = 0;
  for (int k0 = 0; k0 < K; k0 += 32) {
    if (k0 + 32 < K) stage(cur ^ 1, k0 + 32);
    bf16x8 a[4], b[4];
#pragma unroll
    for (int r = 0; r < 4; r++)
      a[r] = *(const bf16x8*)(As[cur] + (wr + r * 16 + lr) * 32 + 8 * lg);
#pragma unroll
    for (int c = 0; c < 4; c++)
      b[c] = *(const bf16x8*)(Bs[cur] + (wc + c * 16 + lr) * 32 + 8 * lg);
#pragma unroll
    for (int r = 0; r < 4; r++)
#pragma unroll
      for (int c = 0; c < 4; c++)
        acc[r][c] = __builtin_amdgcn_mfma_f32_16x16x32_bf16(a[r], b[c], acc[r][c], 0, 0, 0);
    __syncthreads();
    cur ^= 1;
  }

#pragma unroll
  for (int r = 0; r < 4; r++)
#pragma unroll
    for (int c = 0; c < 4; c++)
#pragma unroll
      for (int j = 0; j < 4; j++) {
        int m = m0 + wr + r * 16 + lg * 4 + j;
        int n = n0 + wc + c * 16 + lr;
        int b_ = m >> 11, s_ = m & 2047;
        int h_ = n >> 6,  d_ = n & 63;
        u16 vv = f2bf(acc[r][c][j]);
        if (z == 2)
          C[((size_t)(b_ * NHEAD + h_) * DKD + d_) * SEQ + s_] = vv;   // V^T
        else
          C[(((size_t)(b_ * NHEAD + h_) * SEQ + s_) << 6) + d_] = vv;  // heads
      }
}

// ---------------- output GEMM (B^T), BM=64 x BN=128, dbuf, fp32 out -------
__global__ __launch_bounds__(256)
void gemm_out(const u16* __restrict__ A, const u16* __restrict__ B,
              float* __restrict__ C) {
  constexpr int K = EMBED, N = EMBED;
  __shared__ u16 As[2][64 * 32];
  __shared__ u16 Bs[2][128 * 32];
  const int t = threadIdx.x;
  const int w = t >> 6, l = t & 63;
  const int lr = l & 15, lg = l >> 4;
  const int m0 = blockIdx.x * 64;
  const int n0 = blockIdx.y * 128;
  const int wr = (w >> 1) * 32, wc = (w & 1) * 64;

  f32x4 acc[2][4] = {};

  const int srow = t >> 2;
  const int scol = (t & 3) * 8;
  const u16* Ag = A + (size_t)(m0 + srow) * K + scol;
  const u16* Bg = B + (size_t)(n0 + srow) * K + scol;
  const size_t rowstep = (size_t)64 * K;

  auto stage = [&](int buf, int k0) {
    gload_lds16(Ag + k0,           As[buf] + w * 512);
    gload_lds16(Bg + k0,           Bs[buf] + w * 512);
    gload_lds16(Bg + k0 + rowstep, Bs[buf] + 64 * 32 + w * 512);
  };

  stage(0, 0);
  __syncthreads();
  int cur = 0;
  for (int k0 = 0; k0 < K; k0 += 32) {
    if (k0 + 32 < K) stage(cur ^ 1, k0 + 32);
    bf16x8 a[2], b[4];
#pragma unroll
    for (int r = 0; r < 2; r++)
      a[r] = *(const bf16x8*)(As[cur] + (wr + r * 16 + lr) * 32 + 8 * lg);
#pragma unroll
    for (int c = 0; c < 4; c++)
      b[c] = *(const bf16x8*)(Bs[cur] + (wc + c * 16 + lr) * 32 + 8 * lg);
#pragma unroll
    for (int r = 0; r < 2; r++)
#pragma unroll
      for (int c = 0; c < 4; c++)
        acc[r][c] = __builtin_amdgcn_mfma_f32_16x16x32_bf16(a[r], b[c], acc[r][c], 0, 0, 0);
    __syncthreads();
    cur ^= 1;
  }

#pragma unroll
  for (int r = 0; r < 2; r++)
#pragma unroll
    for (int c = 0; c < 4; c++)
#pragma unroll
      for (int j = 0; j < 4; j++) {
        int m = m0 + wr + r * 16 + lg * 4 + j;
        int n = n0 + wc + c * 16 + lr;
        C[(size_t)m * N + n] = acc[r][c][j];
      }
}

// ---------------- flash attention v4 (verified) + T5 setprio ---------------
// Swapped QK^T (lane q = l&31 owns a full score row) + swapped PV (acc = O^T,
// state lane-local) + cvt_pk/permlane32_swap P-repack (zero P LDS traffic).
// Qh,Kh: [B,H,S,DK] bf16; Vt: [B,H,DK,S] bf16; Xo: [B,S,E] bf16
__global__ __launch_bounds__(256, 2)
void attn_kernel(const u16* __restrict__ Qh, const u16* __restrict__ Kh,
                 const u16* __restrict__ Vt, u16* __restrict__ Xo) {
  __shared__ u16 KV[2][8192];      // per buf: K[64 kv][64 d] | V^T[64 d][64 kv], XOR-swizzled
  const int t = threadIdx.x, w = t >> 6, l = t & 63;
  const int q32 = l & 31, h = l >> 5;
  // XCD-clustered decode: XCD k owns bh in {4k..4k+3}
  const int xcd = blockIdx.x & 7;
  const int li  = blockIdx.x >> 3;          // 0..63
  const int bh  = xcd * 4 + (li >> 4);
  const int qblk = li & 15;
  const int b_ = bh >> 4, h_ = bh & 15;
  const size_t base = (size_t)bh * SEQ * DKD;
  const u16* Kb = Kh + base;
  const u16* Vb = Vt + base;                // [DK][SEQ]
  constexpr int NT = SEQ / 64;              // 32
  constexpr float C2 = 0.18033688f;         // 0.125 * log2(e)
  constexpr float THR = 44.0f;              // raw-domain defer-max bound (~2^8)

  // Q fragments (B-operand, 32x32x16): lane holds Q[q=q32][d=16ks+8h+e]
  const int qrow = qblk * 128 + w * 32 + q32;
  bf16x8 qf[4];
#pragma unroll
  for (int ks = 0; ks < 4; ks++)
    qf[ks] = *(const bf16x8*)(Qh + base + (size_t)qrow * DKD + ks * 16 + h * 8);

  f32x16 acc[2] = {};                       // O^T: lane q=q32, d=(r&3)+8(r>>2)+4h+32dc
  float m2 = -1e30f, lsum = 0.f;

  auto stage = [&](int buf, int kt) {
    u16* kd = &KV[buf][0];
    u16* vd = &KV[buf][4096];
    const int rb = w * 8 + (l >> 3);        // wave-local row band
    const int sg = (l & 7) ^ (l >> 3);      // pre-swizzled source slot
#pragma unroll
    for (int ch = 0; ch < 2; ch++) {
      int row = ch * 32 + rb;
      gload_lds16(Kb + (size_t)(kt * 64 + row) * DKD + sg * 8,
                  kd + (ch * 32 + w * 8) * 64);
      gload_lds16(Vb + (size_t)row * SEQ + kt * 64 + sg * 8,
                  vd + (ch * 32 + w * 8) * 64);
    }
  };

  auto compute = [&](int buf) {
    const u16* kd = &KV[buf][0];
    const u16* vd = &KV[buf][4096];
    // ---- QK^T swapped: s[c] = S^T[kv=c*32+(r&3)+8(r>>2)+4h][q=q32]
    f32x16 s[2] = {};
    __builtin_amdgcn_s_setprio(1);
#pragma unroll
    for (int c = 0; c < 2; c++) {
      int row = c * 32 + q32;
#pragma unroll
      for (int ks = 0; ks < 4; ks++) {
        bf16x8 kf = *(const bf16x8*)(kd + row * 64 + (((2 * ks + h) ^ (row & 7)) * 8));
        s[c] = __builtin_amdgcn_mfma_f32_32x32x16_bf16(kf, qf[ks], s[c], 0, 0, 0);
      }
    }
    __builtin_amdgcn_s_setprio(0);
    // ---- V fragments early (hide ds latency under softmax VALU)
    bf16x8 vf[2][4];
#pragma unroll
    for (int dc = 0; dc < 2; dc++) {
      int row = dc * 32 + q32;
#pragma unroll
      for (int tile = 0; tile < 4; tile++)
        vf[dc][tile] = *(const bf16x8*)(vd + row * 64 + (((2 * tile + h) ^ (row & 7)) * 8));
    }
    // ---- per-lane max over this tile's 32 scores (raw domain)
    float pm = s[0][0];
#pragma unroll
    for (int r = 1; r < 16; r++) pm = fmaxf(pm, s[0][r]);
#pragma unroll
    for (int r = 0; r < 16; r++) pm = fmaxf(pm, s[1][r]);
    if (__any(pm > m2 + THR)) {             // defer-max trigger (rare)
      float pmo = __shfl_xor(pm, 32, 64);   // true row max needs both halves
      float mn = fmaxf(m2, fmaxf(pm, pmo));
      float al = __builtin_amdgcn_exp2f((m2 - mn) * C2);
      lsum *= al;
#pragma unroll
      for (int dc = 0; dc < 2; dc++)
#pragma unroll
        for (int r = 0; r < 16; r++) acc[dc][r] *= al;
      m2 = mn;
    }
    // ---- P = exp2((s-m)*C2); pack + permlane-swap into PV B-fragments
    const float nm = -m2 * C2;
    bf16x8 pfrag[4];
    float ls = 0.f;
#pragma unroll
    for (int c = 0; c < 2; c++) {
      float p[16];
#pragma unroll
      for (int r = 0; r < 16; r++) {
        p[r] = __builtin_amdgcn_exp2f(__builtin_fmaf(s[c][r], C2, nm));
        ls += p[r];
      }
      u32 Pk[8];
#pragma unroll
      for (int i = 0; i < 8; i++) Pk[i] = cvtpk(p[2 * i], p[2 * i + 1]);
      plswap(Pk[0], Pk[2]); plswap(Pk[1], Pk[3]);
      plswap(Pk[4], Pk[6]); plswap(Pk[5], Pk[7]);
      pfrag[2 * c]     = __builtin_bit_cast(bf16x8, (u32x4){Pk[0], Pk[1], Pk[2], Pk[3]});
      pfrag[2 * c + 1] = __builtin_bit_cast(bf16x8, (u32x4){Pk[4], Pk[5], Pk[6], Pk[7]});
    }
    lsum += ls;
    // ---- PV swapped: acc[dc] += V^T-frag x P-frag  (D = O^T)
    __builtin_amdgcn_s_setprio(1);
#pragma unroll
    for (int tile = 0; tile < 4; tile++)
#pragma unroll
      for (int dc = 0; dc < 2; dc++)
        acc[dc] = __builtin_amdgcn_mfma_f32_32x32x16_bf16(vf[dc][tile], pfrag[tile], acc[dc], 0, 0, 0);
    __builtin_amdgcn_s_setprio(0);
  };

  stage(0, 0);
  __syncthreads();
  int cur = 0;
  for (int kt = 0; kt < NT; kt++) {
    if (kt + 1 < NT) stage(cur ^ 1, kt + 1);
    compute(cur);
    __syncthreads();
    cur ^= 1;
  }

  // ---- epilogue: combine halves' lsum, normalize (all lane-local), store
  lsum += __shfl_xor(lsum, 32, 64);
  float inv = 1.0f / lsum;
  u16* orow = Xo + ((size_t)b_ * SEQ + qrow) * EMBED + h_ * DKD;
#pragma unroll
  for (int dc = 0; dc < 2; dc++)
#pragma unroll
    for (int k4 = 0; k4 < 4; k4++) {
      u32 w0 = cvtpk(acc[dc][4 * k4 + 0] * inv, acc[dc][4 * k4 + 1] * inv);
      u32 w1 = cvtpk(acc[dc][4 * k4 + 2] * inv, acc[dc][4 * k4 + 3] * inv);
      int d = dc * 32 + k4 * 8 + h * 4;
      uint2 pk; pk.x = w0; pk.y = w1;
      *(uint2*)(orow + d) = pk;
    }
}

extern "C" void kernel_launch(void* const* d_in, const int* in_sizes, int n_in,
                              void* d_out, int out_size, void* d_ws, size_t ws_size,
                              hipStream_t stream) {
  const float* q  = (const float*)d_in[0];
  const float* k  = (const float*)d_in[1];
  const float* v  = (const float*)d_in[2];
  const float* Wq = (const float*)d_in[3];
  const float* Wk = (const float*)d_in[4];
  const float* Wv = (const float*)d_in[5];
  const float* Wo = (const float*)d_in[6];

  char* ws = (char*)d_ws;
  const size_t SZ_X = (size_t)MROWS * EMBED * 2;   // 8 MiB
  const size_t SZ_W = (size_t)EMBED * EMBED * 2;   // 2 MiB
  u16* qbf  = (u16*)(ws);
  u16* kbf  = (u16*)(ws + SZ_X);
  u16* vbf  = (u16*)(ws + 2 * SZ_X);
  u16* wqb  = (u16*)(ws + 3 * SZ_X);
  u16* wkb  = (u16*)(ws + 3 * SZ_X + SZ_W);
  u16* wvb  = (u16*)(ws + 3 * SZ_X + 2 * SZ_W);
  u16* wob  = (u16*)(ws + 3 * SZ_X + 3 * SZ_W);
  u16* Qh   = (u16*)(ws + 3 * SZ_X + 4 * SZ_W);
  u16* Kh   = (u16*)(ws + 4 * SZ_X + 4 * SZ_W);
  u16* Vt   = (u16*)(ws + 5 * SZ_X + 4 * SZ_W);
  u16* Xcat = (u16*)(ws + 6 * SZ_X + 4 * SZ_W);    // total 64 MiB

  cast_all<<<dim3(1024, 7), 256, 0, stream>>>(q, k, v, Wq, Wk, Wv, Wo,
                                              qbf, kbf, vbf, wqb, wkb, wvb, wob);

  gemm_qkv<<<dim3(MROWS / 128, EMBED / 128, 3), 256, 0, stream>>>(
      qbf, kbf, vbf, wqb, wkb, wvb, Qh, Kh, Vt);

  attn_kernel<<<512, 256, 0, stream>>>(Qh, Kh, Vt, Xcat);

  gemm_out<<<dim3(MROWS / 64, EMBED / 128), 256, 0, stream>>>(Xcat, wob, (float*)d_out);
}

// Round 10
// 121.777 us; speedup vs baseline: 1.2058x; 1.0879x over previous
//
#include <hip/hip_runtime.h>
#include <hip/hip_bf16.h>
#include <stdint.h>

#define EMBED 1024
#define NHEAD 16
#define DKD   64
#define BATCH 2
#define SEQ   2048
#define MROWS (BATCH*SEQ)   // 4096

typedef __attribute__((ext_vector_type(8)))  short bf16x8;
typedef __attribute__((ext_vector_type(4)))  float f32x4;
typedef __attribute__((ext_vector_type(16))) float f32x16;
typedef unsigned short u16;
typedef unsigned int   u32;
typedef __attribute__((ext_vector_type(4))) u32 u32x4;

__device__ inline u16 f2bf(float f) {
  return __builtin_bit_cast(u16, __float2bfloat16(f));  // single v_cvt, RNE
}

__device__ inline u32 cvtpk(float lo, float hi) {   // lo->bits[15:0], hi->bits[31:16]
  u32 r;
  asm("v_cvt_pk_bf16_f32 %0, %1, %2" : "=v"(r) : "v"(lo), "v"(hi));
  return r;
}

// X' = (h0: X_h0, h1: Y_h0) ; Y' = (h0: X_h1, h1: Y_h1)   [vdst.row1 <-> vsrc.row0]
__device__ inline void plswap(u32& x, u32& y) {
  asm volatile("v_permlane32_swap_b32 %0, %1" : "+v"(x), "+v"(y));
}

__device__ inline void gload_lds16(const u16* g, u16* l) {
  __builtin_amdgcn_global_load_lds(
      (const __attribute__((address_space(1))) u32*)(const void*)g,
      (__attribute__((address_space(3))) u32*)(void*)l, 16, 0, 0);
}

// ---------------- fused cast fp32 -> bf16 (all 7 tensors, 1 launch) --------
__global__ __launch_bounds__(256) void cast_all(
    const float* __restrict__ s0, const float* __restrict__ s1,
    const float* __restrict__ s2, const float* __restrict__ s3,
    const float* __restrict__ s4, const float* __restrict__ s5,
    const float* __restrict__ s6,
    u16* __restrict__ d0, u16* __restrict__ d1, u16* __restrict__ d2,
    u16* __restrict__ d3, u16* __restrict__ d4, u16* __restrict__ d5,
    u16* __restrict__ d6) {
  const int y = blockIdx.y;
  const float* s; u16* d; int n4;
  switch (y) {
    case 0: s = s0; d = d0; n4 = MROWS*EMBED/4; break;
    case 1: s = s1; d = d1; n4 = MROWS*EMBED/4; break;
    case 2: s = s2; d = d2; n4 = MROWS*EMBED/4; break;
    case 3: s = s3; d = d3; n4 = EMBED*EMBED/4; break;
    case 4: s = s4; d = d4; n4 = EMBED*EMBED/4; break;
    case 5: s = s5; d = d5; n4 = EMBED*EMBED/4; break;
    default: s = s6; d = d6; n4 = EMBED*EMBED/4; break;
  }
  int i = blockIdx.x * 256 + threadIdx.x;
  int stride = gridDim.x * 256;
  for (int idx = i; idx < n4; idx += stride) {
    float4 f = ((const float4*)s)[idx];
    ushort4 o;
    o.x = f2bf(f.x); o.y = f2bf(f.y); o.z = f2bf(f.z); o.w = f2bf(f.w);
    ((ushort4*)d)[idx] = o;
  }
}

// ---------------- fused QKV projection GEMM (B^T), BM=128, grid.z selects --
__global__ __launch_bounds__(256)
void gemm_qkv(const u16* __restrict__ A0, const u16* __restrict__ A1,
              const u16* __restrict__ A2, const u16* __restrict__ B0,
              const u16* __restrict__ B1, const u16* __restrict__ B2,
              u16* __restrict__ C0, u16* __restrict__ C1, u16* __restrict__ C2) {
  constexpr int K = EMBED;
  __shared__ u16 As[128 * 32];
  __shared__ u16 Bs[128 * 32];
  const int z = blockIdx.z;
  const u16* A = (z == 0) ? A0 : (z == 1) ? A1 : A2;
  const u16* B = (z == 0) ? B0 : (z == 1) ? B1 : B2;
  u16* C       = (z == 0) ? C0 : (z == 1) ? C1 : C2;

  const int t = threadIdx.x;
  const int w = t >> 6, l = t & 63;
  const int lr = l & 15, lg = l >> 4;
  const int m0 = blockIdx.x * 128;
  const int n0 = blockIdx.y * 128;
  const int wr = (w >> 1) * 64, wc = (w & 1) * 64;

  f32x4 acc[4][4] = {};

  const int srow = t >> 2;
  const int scol = (t & 3) * 8;
  const u16* Ag = A + (size_t)(m0 + srow) * K + scol;
  const u16* Bg = B + (size_t)(n0 + srow) * K + scol;
  u16* AsW = As + w * 512;
  u16* BsW = Bs + w * 512;
  const size_t rowstep = (size_t)64 * K;

  for (int k0 = 0; k0 < K; k0 += 32) {
    gload_lds16(Ag + k0,           AsW);
    gload_lds16(Ag + k0 + rowstep, AsW + 64 * 32);
    gload_lds16(Bg + k0,           BsW);
    gload_lds16(Bg + k0 + rowstep, BsW + 64 * 32);
    __syncthreads();
    bf16x8 a[4], b[4];
#pragma unroll
    for (int r = 0; r < 4; r++)
      a[r] = *(const bf16x8*)(As + (wr + r * 16 + lr) * 32 + 8 * lg);
#pragma unroll
    for (int c = 0; c < 4; c++)
      b[c] = *(const bf16x8*)(Bs + (wc + c * 16 + lr) * 32 + 8 * lg);
#pragma unroll
    for (int r = 0; r < 4; r++)
#pragma unroll
      for (int c = 0; c < 4; c++)
        acc[r][c] = __builtin_amdgcn_mfma_f32_16x16x32_bf16(a[r], b[c], acc[r][c], 0, 0, 0);
    __syncthreads();
  }

#pragma unroll
  for (int r = 0; r < 4; r++)
#pragma unroll
    for (int c = 0; c < 4; c++)
#pragma unroll
      for (int j = 0; j < 4; j++) {
        int m = m0 + wr + r * 16 + lg * 4 + j;
        int n = n0 + wc + c * 16 + lr;
        int b_ = m >> 11, s_ = m & 2047;
        int h_ = n >> 6,  d_ = n & 63;
        u16 vv = f2bf(acc[r][c][j]);
        if (z == 2)
          C[((size_t)(b_ * NHEAD + h_) * DKD + d_) * SEQ + s_] = vv;   // V^T
        else
          C[(((size_t)(b_ * NHEAD + h_) * SEQ + s_) << 6) + d_] = vv;  // heads
      }
}

// ---------------- output GEMM (B^T), BM=64 x BN=128, fp32 out -------------
__global__ __launch_bounds__(256)
void gemm_out(const u16* __restrict__ A, const u16* __restrict__ B,
              float* __restrict__ C) {
  constexpr int K = EMBED, N = EMBED;
  __shared__ u16 As[64 * 32];
  __shared__ u16 Bs[128 * 32];
  const int t = threadIdx.x;
  const int w = t >> 6, l = t & 63;
  const int lr = l & 15, lg = l >> 4;
  const int m0 = blockIdx.x * 64;
  const int n0 = blockIdx.y * 128;
  const int wr = (w >> 1) * 32, wc = (w & 1) * 64;

  f32x4 acc[2][4] = {};

  const int srow = t >> 2;
  const int scol = (t & 3) * 8;
  const u16* Ag = A + (size_t)(m0 + srow) * K + scol;
  const u16* Bg = B + (size_t)(n0 + srow) * K + scol;
  u16* AsW = As + w * 512;
  u16* BsW = Bs + w * 512;
  const size_t rowstep = (size_t)64 * K;

  for (int k0 = 0; k0 < K; k0 += 32) {
    gload_lds16(Ag + k0,           AsW);
    gload_lds16(Bg + k0,           BsW);
    gload_lds16(Bg + k0 + rowstep, BsW + 64 * 32);
    __syncthreads();
    bf16x8 a[2], b[4];
#pragma unroll
    for (int r = 0; r < 2; r++)
      a[r] = *(const bf16x8*)(As + (wr + r * 16 + lr) * 32 + 8 * lg);
#pragma unroll
    for (int c = 0; c < 4; c++)
      b[c] = *(const bf16x8*)(Bs + (wc + c * 16 + lr) * 32 + 8 * lg);
#pragma unroll
    for (int r = 0; r < 2; r++)
#pragma unroll
      for (int c = 0; c < 4; c++)
        acc[r][c] = __builtin_amdgcn_mfma_f32_16x16x32_bf16(a[r], b[c], acc[r][c], 0, 0, 0);
    __syncthreads();
  }

#pragma unroll
  for (int r = 0; r < 2; r++)
#pragma unroll
    for (int c = 0; c < 4; c++)
#pragma unroll
      for (int j = 0; j < 4; j++) {
        int m = m0 + wr + r * 16 + lg * 4 + j;
        int n = n0 + wc + c * 16 + lr;
        C[(size_t)m * N + n] = acc[r][c][j];
      }
}

// ---------------- flash attention v9: two-tile in-wave pipeline ------------
// v4's per-tile math verbatim, but KV tiles processed in pairs with 4 LDS
// slots: QK_A,QK_B issued back-to-back (matrix pipe fills), softmax_A (VALU)
// overlaps QK_B drain, softmax_B overlaps PV_A. One barrier per 2 tiles.
// Qh,Kh: [B,H,S,DK] bf16; Vt: [B,H,DK,S] bf16; Xo: [B,S,E] bf16
__global__ __launch_bounds__(256, 2)
void attn_kernel(const u16* __restrict__ Qh, const u16* __restrict__ Kh,
                 const u16* __restrict__ Vt, u16* __restrict__ Xo) {
  __shared__ u16 KV[4][8192];      // 4 slots: K[64 kv][64 d] | V^T[64 d][64 kv], XOR-swizzled
  const int t = threadIdx.x, w = t >> 6, l = t & 63;
  const int q32 = l & 31, h = l >> 5;
  // XCD-clustered decode: XCD k owns bh in {4k..4k+3}
  const int xcd = blockIdx.x & 7;
  const int li  = blockIdx.x >> 3;          // 0..63
  const int bh  = xcd * 4 + (li >> 4);
  const int qblk = li & 15;
  const int b_ = bh >> 4, h_ = bh & 15;
  const size_t base = (size_t)bh * SEQ * DKD;
  const u16* Kb = Kh + base;
  const u16* Vb = Vt + base;                // [DK][SEQ]
  constexpr int NT = SEQ / 64;              // 32
  constexpr float C2 = 0.18033688f;         // 0.125 * log2(e)
  constexpr float THR = 44.0f;              // raw-domain defer-max bound (~2^8)

  // Q fragments (B-operand, 32x32x16): lane holds Q[q=q32][d=16ks+8h+e]
  const int qrow = qblk * 128 + w * 32 + q32;
  bf16x8 qf[4];
#pragma unroll
  for (int ks = 0; ks < 4; ks++)
    qf[ks] = *(const bf16x8*)(Qh + base + (size_t)qrow * DKD + ks * 16 + h * 8);

  f32x16 acc[2] = {};                       // O^T: lane q=q32, d=(r&3)+8(r>>2)+4h+32dc
  float m2 = -1e30f, lsum = 0.f;

  auto stage = [&](int slot, int kt) {
    u16* kd = &KV[slot][0];
    u16* vd = &KV[slot][4096];
    const int rb = w * 8 + (l >> 3);        // wave-local row band
    const int sg = (l & 7) ^ (l >> 3);      // pre-swizzled source slot
#pragma unroll
    for (int ch = 0; ch < 2; ch++) {
      int row = ch * 32 + rb;
      gload_lds16(Kb + (size_t)(kt * 64 + row) * DKD + sg * 8,
                  kd + (ch * 32 + w * 8) * 64);
      gload_lds16(Vb + (size_t)row * SEQ + kt * 64 + sg * 8,
                  vd + (ch * 32 + w * 8) * 64);
    }
  };

  // ---- v4 per-tile pieces (verbatim math) ----
  auto qk = [&](const u16* kd, f32x16 (&s)[2]) {
#pragma unroll
    for (int c = 0; c < 2; c++) {
      int row = c * 32 + q32;
#pragma unroll
      for (int ks = 0; ks < 4; ks++) {
        bf16x8 kf = *(const bf16x8*)(kd + row * 64 + (((2 * ks + h) ^ (row & 7)) * 8));
        s[c] = __builtin_amdgcn_mfma_f32_32x32x16_bf16(kf, qf[ks], s[c], 0, 0, 0);
      }
    }
  };
  auto vload = [&](const u16* vd, bf16x8 (&vf)[2][4]) {
#pragma unroll
    for (int dc = 0; dc < 2; dc++) {
      int row = dc * 32 + q32;
#pragma unroll
      for (int tile = 0; tile < 4; tile++)
        vf[dc][tile] = *(const bf16x8*)(vd + row * 64 + (((2 * tile + h) ^ (row & 7)) * 8));
    }
  };
  auto softmax_pack = [&](f32x16 (&s)[2], bf16x8 (&pfrag)[4]) {
    float pm = s[0][0];
#pragma unroll
    for (int r = 1; r < 16; r++) pm = fmaxf(pm, s[0][r]);
#pragma unroll
    for (int r = 0; r < 16; r++) pm = fmaxf(pm, s[1][r]);
    if (__any(pm > m2 + THR)) {             // defer-max trigger (rare)
      float pmo = __shfl_xor(pm, 32, 64);   // true row max needs both halves
      float mn = fmaxf(m2, fmaxf(pm, pmo));
      float al = __builtin_amdgcn_exp2f((m2 - mn) * C2);
      lsum *= al;
#pragma unroll
      for (int dc = 0; dc < 2; dc++)
#pragma unroll
        for (int r = 0; r < 16; r++) acc[dc][r] *= al;
      m2 = mn;
    }
    const float nm = -m2 * C2;
    float ls = 0.f;
#pragma unroll
    for (int c = 0; c < 2; c++) {
      float p[16];
#pragma unroll
      for (int r = 0; r < 16; r++) {
        p[r] = __builtin_amdgcn_exp2f(__builtin_fmaf(s[c][r], C2, nm));
        ls += p[r];
      }
      u32 Pk[8];
#pragma unroll
      for (int i = 0; i < 8; i++) Pk[i] = cvtpk(p[2 * i], p[2 * i + 1]);
      plswap(Pk[0], Pk[2]); plswap(Pk[1], Pk[3]);
      plswap(Pk[4], Pk[6]); plswap(Pk[5], Pk[7]);
      pfrag[2 * c]     = __builtin_bit_cast(bf16x8, (u32x4){Pk[0], Pk[1], Pk[2], Pk[3]});
      pfrag[2 * c + 1] = __builtin_bit_cast(bf16x8, (u32x4){Pk[4], Pk[5], Pk[6], Pk[7]});
    }
    lsum += ls;
  };
  auto pv = [&](bf16x8 (&vf)[2][4], bf16x8 (&pfrag)[4]) {
#pragma unroll
    for (int tile = 0; tile < 4; tile++)
#pragma unroll
      for (int dc = 0; dc < 2; dc++)
        acc[dc] = __builtin_amdgcn_mfma_f32_32x32x16_bf16(vf[dc][tile], pfrag[tile], acc[dc], 0, 0, 0);
  };

  // prologue: stage tiles 0,1 into slots 0,1
  stage(0, 0);
  stage(1, 1);
  __syncthreads();

  for (int kt = 0; kt < NT; kt += 2) {
    const int sA = kt & 3, sB = (kt + 1) & 3;
    // prefetch tiles kt+2, kt+3 into the slots freed at the last barrier
    if (kt + 2 < NT) {
      stage((kt + 2) & 3, kt + 2);
      stage((kt + 3) & 3, kt + 3);
    }
    // two-tile pipeline: QK_A, QK_B fill the matrix pipe; softmax_A (VALU)
    // overlaps QK_B drain; softmax_B overlaps PV_A.
    f32x16 scA[2] = {}, scB[2] = {};
    qk(&KV[sA][0], scA);
    qk(&KV[sB][0], scB);
    bf16x8 vfA[2][4];
    vload(&KV[sA][4096], vfA);
    bf16x8 pfA[4];
    softmax_pack(scA, pfA);
    pv(vfA, pfA);
    bf16x8 vfB[2][4];
    vload(&KV[sB][4096], vfB);
    bf16x8 pfB[4];
    softmax_pack(scB, pfB);
    pv(vfB, pfB);
    __syncthreads();
  }

  // ---- epilogue: combine halves' lsum, normalize (all lane-local), store
  lsum += __shfl_xor(lsum, 32, 64);
  float inv = 1.0f / lsum;
  u16* orow = Xo + ((size_t)b_ * SEQ + qrow) * EMBED + h_ * DKD;
#pragma unroll
  for (int dc = 0; dc < 2; dc++)
#pragma unroll
    for (int k4 = 0; k4 < 4; k4++) {
      u32 w0 = cvtpk(acc[dc][4 * k4 + 0] * inv, acc[dc][4 * k4 + 1] * inv);
      u32 w1 = cvtpk(acc[dc][4 * k4 + 2] * inv, acc[dc][4 * k4 + 3] * inv);
      int d = dc * 32 + k4 * 8 + h * 4;
      uint2 pk; pk.x = w0; pk.y = w1;
      *(uint2*)(orow + d) = pk;
    }
}

extern "C" void kernel_launch(void* const* d_in, const int* in_sizes, int n_in,
                              void* d_out, int out_size, void* d_ws, size_t ws_size,
                              hipStream_t stream) {
  const float* q  = (const float*)d_in[0];
  const float* k  = (const float*)d_in[1];
  const float* v  = (const float*)d_in[2];
  const float* Wq = (const float*)d_in[3];
  const float* Wk = (const float*)d_in[4];
  const float* Wv = (const float*)d_in[5];
  const float* Wo = (const float*)d_in[6];

  char* ws = (char*)d_ws;
  const size_t SZ_X = (size_t)MROWS * EMBED * 2;   // 8 MiB
  const size_t SZ_W = (size_t)EMBED * EMBED * 2;   // 2 MiB
  u16* qbf  = (u16*)(ws);
  u16* kbf  = (u16*)(ws + SZ_X);
  u16* vbf  = (u16*)(ws + 2 * SZ_X);
  u16* wqb  = (u16*)(ws + 3 * SZ_X);
  u16* wkb  = (u16*)(ws + 3 * SZ_X + SZ_W);
  u16* wvb  = (u16*)(ws + 3 * SZ_X + 2 * SZ_W);
  u16* wob  = (u16*)(ws + 3 * SZ_X + 3 * SZ_W);
  u16* Qh   = (u16*)(ws + 3 * SZ_X + 4 * SZ_W);
  u16* Kh   = (u16*)(ws + 4 * SZ_X + 4 * SZ_W);
  u16* Vt   = (u16*)(ws + 5 * SZ_X + 4 * SZ_W);
  u16* Xcat = (u16*)(ws + 6 * SZ_X + 4 * SZ_W);    // total 64 MiB

  cast_all<<<dim3(1024, 7), 256, 0, stream>>>(q, k, v, Wq, Wk, Wv, Wo,
                                              qbf, kbf, vbf, wqb, wkb, wvb, wob);

  gemm_qkv<<<dim3(MROWS / 128, EMBED / 128, 3), 256, 0, stream>>>(
      qbf, kbf, vbf, wqb, wkb, wvb, Qh, Kh, Vt);

  attn_kernel<<<512, 256, 0, stream>>>(Qh, Kh, Vt, Xcat);

  gemm_out<<<dim3(MROWS / 64, EMBED / 128), 256, 0, stream>>>(Xcat, wob, (float*)d_out);
}

// Round 11
// 116.040 us; speedup vs baseline: 1.2654x; 1.0494x over previous
//
#include <hip/hip_runtime.h>
#include <hip/hip_bf16.h>
#include <stdint.h>

#define EMBED 1024
#define NHEAD 16
#define DKD   64
#define BATCH 2
#define SEQ   2048
#define MROWS (BATCH*SEQ)   // 4096

typedef __attribute__((ext_vector_type(8)))  short bf16x8;
typedef __attribute__((ext_vector_type(4)))  float f32x4;
typedef __attribute__((ext_vector_type(16))) float f32x16;
typedef unsigned short u16;
typedef unsigned int   u32;
typedef __attribute__((ext_vector_type(4))) u32 u32x4;

__device__ inline u16 f2bf(float f) {
  return __builtin_bit_cast(u16, __float2bfloat16(f));  // single v_cvt, RNE
}

__device__ inline u32 cvtpk(float lo, float hi) {   // lo->bits[15:0], hi->bits[31:16]
  u32 r;
  asm("v_cvt_pk_bf16_f32 %0, %1, %2" : "=v"(r) : "v"(lo), "v"(hi));
  return r;
}

// X' = (h0: X_h0, h1: Y_h0) ; Y' = (h0: X_h1, h1: Y_h1)   [vdst.row1 <-> vsrc.row0]
__device__ inline void plswap(u32& x, u32& y) {
  asm volatile("v_permlane32_swap_b32 %0, %1" : "+v"(x), "+v"(y));
}

__device__ inline void gload_lds16(const u16* g, u16* l) {
  __builtin_amdgcn_global_load_lds(
      (const __attribute__((address_space(1))) u32*)(const void*)g,
      (__attribute__((address_space(3))) u32*)(void*)l, 16, 0, 0);
}

// ---------------- cast fp32 -> bf16 (4 weight tensors only) ----------------
__global__ __launch_bounds__(256) void cast_w(
    const float* __restrict__ s0, const float* __restrict__ s1,
    const float* __restrict__ s2, const float* __restrict__ s3,
    u16* __restrict__ d0, u16* __restrict__ d1, u16* __restrict__ d2,
    u16* __restrict__ d3) {
  const int y = blockIdx.y;
  const float* s = (y == 0) ? s0 : (y == 1) ? s1 : (y == 2) ? s2 : s3;
  u16* d        = (y == 0) ? d0 : (y == 1) ? d1 : (y == 2) ? d2 : d3;
  constexpr int n4 = EMBED * EMBED / 4;
  int i = blockIdx.x * 256 + threadIdx.x;
  int stride = gridDim.x * 256;
  for (int idx = i; idx < n4; idx += stride) {
    float4 f = ((const float4*)s)[idx];
    ushort4 o;
    o.x = f2bf(f.x); o.y = f2bf(f.y); o.z = f2bf(f.z); o.w = f2bf(f.w);
    ((ushort4*)d)[idx] = o;
  }
}

// ---------------- fused QKV projection GEMM, fp32-A fused cast -------------
// A: fp32 [M,K] (q/k/v inputs, cast fused into reg-staging); B: bf16 [N,K].
// z=0,1 -> [b,h,s,dk] bf16; z=2 -> [b,h,dk,s] (V^T)
__global__ __launch_bounds__(256)
void gemm_qkv(const float* __restrict__ A0, const float* __restrict__ A1,
              const float* __restrict__ A2, const u16* __restrict__ B0,
              const u16* __restrict__ B1, const u16* __restrict__ B2,
              u16* __restrict__ C0, u16* __restrict__ C1, u16* __restrict__ C2) {
  constexpr int K = EMBED;
  __shared__ u16 As[128 * 32];
  __shared__ u16 Bs[128 * 32];
  const int z = blockIdx.z;
  const float* A = (z == 0) ? A0 : (z == 1) ? A1 : A2;
  const u16* B   = (z == 0) ? B0 : (z == 1) ? B1 : B2;
  u16* C         = (z == 0) ? C0 : (z == 1) ? C1 : C2;

  const int t = threadIdx.x;
  const int w = t >> 6, l = t & 63;
  const int lr = l & 15, lg = l >> 4;
  const int m0 = blockIdx.x * 128;
  const int n0 = blockIdx.y * 128;
  const int wr = (w >> 1) * 64, wc = (w & 1) * 64;

  f32x4 acc[4][4] = {};

  const int srow = t >> 2;             // 0..63
  const int scol = (t & 3) * 8;        // 0,8,16,24 (elements)
  const float* Agf = A + (size_t)(m0 + srow) * K + scol;
  const u16*   Bg  = B + (size_t)(n0 + srow) * K + scol;
  u16* BsW = Bs + w * 512;
  const size_t rowstep = (size_t)64 * K;

  // A reg-staging: thread t owns the 16B LDS slot at As + w*512 + l*8
  // (rows srow / srow+64, cols scol..scol+7) — same layout gload_lds made.
  auto loadA = [&](float4 (&f)[4], int k0) {
    f[0] = *(const float4*)(Agf + k0);
    f[1] = *(const float4*)(Agf + k0 + 4);
    f[2] = *(const float4*)(Agf + k0 + rowstep);
    f[3] = *(const float4*)(Agf + k0 + rowstep + 4);
  };

  float4 fa[4];
  loadA(fa, 0);
  for (int k0 = 0; k0 < K; k0 += 32) {
    u32x4 pa0 = {cvtpk(fa[0].x, fa[0].y), cvtpk(fa[0].z, fa[0].w),
                 cvtpk(fa[1].x, fa[1].y), cvtpk(fa[1].z, fa[1].w)};
    u32x4 pa1 = {cvtpk(fa[2].x, fa[2].y), cvtpk(fa[2].z, fa[2].w),
                 cvtpk(fa[3].x, fa[3].y), cvtpk(fa[3].z, fa[3].w)};
    *(u32x4*)(As + w * 512 + l * 8)        = pa0;
    *(u32x4*)(As + 2048 + w * 512 + l * 8) = pa1;
    gload_lds16(Bg + k0,           BsW);
    gload_lds16(Bg + k0 + rowstep, BsW + 64 * 32);
    if (k0 + 32 < K) loadA(fa, k0 + 32);   // prefetch next (hides under compute)
    __syncthreads();
    bf16x8 a[4], b[4];
#pragma unroll
    for (int r = 0; r < 4; r++)
      a[r] = *(const bf16x8*)(As + (wr + r * 16 + lr) * 32 + 8 * lg);
#pragma unroll
    for (int c = 0; c < 4; c++)
      b[c] = *(const bf16x8*)(Bs + (wc + c * 16 + lr) * 32 + 8 * lg);
#pragma unroll
    for (int r = 0; r < 4; r++)
#pragma unroll
      for (int c = 0; c < 4; c++)
        acc[r][c] = __builtin_amdgcn_mfma_f32_16x16x32_bf16(a[r], b[c], acc[r][c], 0, 0, 0);
    __syncthreads();
  }

#pragma unroll
  for (int r = 0; r < 4; r++)
#pragma unroll
    for (int c = 0; c < 4; c++)
#pragma unroll
      for (int j = 0; j < 4; j++) {
        int m = m0 + wr + r * 16 + lg * 4 + j;
        int n = n0 + wc + c * 16 + lr;
        int b_ = m >> 11, s_ = m & 2047;
        int h_ = n >> 6,  d_ = n & 63;
        u16 vv = f2bf(acc[r][c][j]);
        if (z == 2)
          C[((size_t)(b_ * NHEAD + h_) * DKD + d_) * SEQ + s_] = vv;   // V^T
        else
          C[(((size_t)(b_ * NHEAD + h_) * SEQ + s_) << 6) + d_] = vv;  // heads
      }
}

// ---------------- output GEMM (B^T), BM=64 x BN=128, fp32 out -------------
__global__ __launch_bounds__(256)
void gemm_out(const u16* __restrict__ A, const u16* __restrict__ B,
              float* __restrict__ C) {
  constexpr int K = EMBED, N = EMBED;
  __shared__ u16 As[64 * 32];
  __shared__ u16 Bs[128 * 32];
  const int t = threadIdx.x;
  const int w = t >> 6, l = t & 63;
  const int lr = l & 15, lg = l >> 4;
  const int m0 = blockIdx.x * 64;
  const int n0 = blockIdx.y * 128;
  const int wr = (w >> 1) * 32, wc = (w & 1) * 64;

  f32x4 acc[2][4] = {};

  const int srow = t >> 2;
  const int scol = (t & 3) * 8;
  const u16* Ag = A + (size_t)(m0 + srow) * K + scol;
  const u16* Bg = B + (size_t)(n0 + srow) * K + scol;
  u16* AsW = As + w * 512;
  u16* BsW = Bs + w * 512;
  const size_t rowstep = (size_t)64 * K;

  for (int k0 = 0; k0 < K; k0 += 32) {
    gload_lds16(Ag + k0,           AsW);
    gload_lds16(Bg + k0,           BsW);
    gload_lds16(Bg + k0 + rowstep, BsW + 64 * 32);
    __syncthreads();
    bf16x8 a[2], b[4];
#pragma unroll
    for (int r = 0; r < 2; r++)
      a[r] = *(const bf16x8*)(As + (wr + r * 16 + lr) * 32 + 8 * lg);
#pragma unroll
    for (int c = 0; c < 4; c++)
      b[c] = *(const bf16x8*)(Bs + (wc + c * 16 + lr) * 32 + 8 * lg);
#pragma unroll
    for (int r = 0; r < 2; r++)
#pragma unroll
      for (int c = 0; c < 4; c++)
        acc[r][c] = __builtin_amdgcn_mfma_f32_16x16x32_bf16(a[r], b[c], acc[r][c], 0, 0, 0);
    __syncthreads();
  }

#pragma unroll
  for (int r = 0; r < 2; r++)
#pragma unroll
    for (int c = 0; c < 4; c++)
#pragma unroll
      for (int j = 0; j < 4; j++) {
        int m = m0 + wr + r * 16 + lg * 4 + j;
        int n = n0 + wc + c * 16 + lr;
        C[(size_t)m * N + n] = acc[r][c][j];
      }
}

// ---------------- flash attention v9: two-tile in-wave pipeline ------------
// (unchanged from round 10 — verified PASS)
__global__ __launch_bounds__(256, 2)
void attn_kernel(const u16* __restrict__ Qh, const u16* __restrict__ Kh,
                 const u16* __restrict__ Vt, u16* __restrict__ Xo) {
  __shared__ u16 KV[4][8192];      // 4 slots: K[64 kv][64 d] | V^T[64 d][64 kv], XOR-swizzled
  const int t = threadIdx.x, w = t >> 6, l = t & 63;
  const int q32 = l & 31, h = l >> 5;
  // XCD-clustered decode: XCD k owns bh in {4k..4k+3}
  const int xcd = blockIdx.x & 7;
  const int li  = blockIdx.x >> 3;          // 0..63
  const int bh  = xcd * 4 + (li >> 4);
  const int qblk = li & 15;
  const int b_ = bh >> 4, h_ = bh & 15;
  const size_t base = (size_t)bh * SEQ * DKD;
  const u16* Kb = Kh + base;
  const u16* Vb = Vt + base;                // [DK][SEQ]
  constexpr int NT = SEQ / 64;              // 32
  constexpr float C2 = 0.18033688f;         // 0.125 * log2(e)
  constexpr float THR = 44.0f;              // raw-domain defer-max bound (~2^8)

  // Q fragments (B-operand, 32x32x16): lane holds Q[q=q32][d=16ks+8h+e]
  const int qrow = qblk * 128 + w * 32 + q32;
  bf16x8 qf[4];
#pragma unroll
  for (int ks = 0; ks < 4; ks++)
    qf[ks] = *(const bf16x8*)(Qh + base + (size_t)qrow * DKD + ks * 16 + h * 8);

  f32x16 acc[2] = {};                       // O^T: lane q=q32, d=(r&3)+8(r>>2)+4h+32dc
  float m2 = -1e30f, lsum = 0.f;

  auto stage = [&](int slot, int kt) {
    u16* kd = &KV[slot][0];
    u16* vd = &KV[slot][4096];
    const int rb = w * 8 + (l >> 3);        // wave-local row band
    const int sg = (l & 7) ^ (l >> 3);      // pre-swizzled source slot
#pragma unroll
    for (int ch = 0; ch < 2; ch++) {
      int row = ch * 32 + rb;
      gload_lds16(Kb + (size_t)(kt * 64 + row) * DKD + sg * 8,
                  kd + (ch * 32 + w * 8) * 64);
      gload_lds16(Vb + (size_t)row * SEQ + kt * 64 + sg * 8,
                  vd + (ch * 32 + w * 8) * 64);
    }
  };

  // ---- v4 per-tile pieces (verbatim math) ----
  auto qk = [&](const u16* kd, f32x16 (&s)[2]) {
#pragma unroll
    for (int c = 0; c < 2; c++) {
      int row = c * 32 + q32;
#pragma unroll
      for (int ks = 0; ks < 4; ks++) {
        bf16x8 kf = *(const bf16x8*)(kd + row * 64 + (((2 * ks + h) ^ (row & 7)) * 8));
        s[c] = __builtin_amdgcn_mfma_f32_32x32x16_bf16(kf, qf[ks], s[c], 0, 0, 0);
      }
    }
  };
  auto vload = [&](const u16* vd, bf16x8 (&vf)[2][4]) {
#pragma unroll
    for (int dc = 0; dc < 2; dc++) {
      int row = dc * 32 + q32;
#pragma unroll
      for (int tile = 0; tile < 4; tile++)
        vf[dc][tile] = *(const bf16x8*)(vd + row * 64 + (((2 * tile + h) ^ (row & 7)) * 8));
    }
  };
  auto softmax_pack = [&](f32x16 (&s)[2], bf16x8 (&pfrag)[4]) {
    float pm = s[0][0];
#pragma unroll
    for (int r = 1; r < 16; r++) pm = fmaxf(pm, s[0][r]);
#pragma unroll
    for (int r = 0; r < 16; r++) pm = fmaxf(pm, s[1][r]);
    if (__any(pm > m2 + THR)) {             // defer-max trigger (rare)
      float pmo = __shfl_xor(pm, 32, 64);   // true row max needs both halves
      float mn = fmaxf(m2, fmaxf(pm, pmo));
      float al = __builtin_amdgcn_exp2f((m2 - mn) * C2);
      lsum *= al;
#pragma unroll
      for (int dc = 0; dc < 2; dc++)
#pragma unroll
        for (int r = 0; r < 16; r++) acc[dc][r] *= al;
      m2 = mn;
    }
    const float nm = -m2 * C2;
    float ls = 0.f;
#pragma unroll
    for (int c = 0; c < 2; c++) {
      float p[16];
#pragma unroll
      for (int r = 0; r < 16; r++) {
        p[r] = __builtin_amdgcn_exp2f(__builtin_fmaf(s[c][r], C2, nm));
        ls += p[r];
      }
      u32 Pk[8];
#pragma unroll
      for (int i = 0; i < 8; i++) Pk[i] = cvtpk(p[2 * i], p[2 * i + 1]);
      plswap(Pk[0], Pk[2]); plswap(Pk[1], Pk[3]);
      plswap(Pk[4], Pk[6]); plswap(Pk[5], Pk[7]);
      pfrag[2 * c]     = __builtin_bit_cast(bf16x8, (u32x4){Pk[0], Pk[1], Pk[2], Pk[3]});
      pfrag[2 * c + 1] = __builtin_bit_cast(bf16x8, (u32x4){Pk[4], Pk[5], Pk[6], Pk[7]});
    }
    lsum += ls;
  };
  auto pv = [&](bf16x8 (&vf)[2][4], bf16x8 (&pfrag)[4]) {
#pragma unroll
    for (int tile = 0; tile < 4; tile++)
#pragma unroll
      for (int dc = 0; dc < 2; dc++)
        acc[dc] = __builtin_amdgcn_mfma_f32_32x32x16_bf16(vf[dc][tile], pfrag[tile], acc[dc], 0, 0, 0);
  };

  // prologue: stage tiles 0,1 into slots 0,1
  stage(0, 0);
  stage(1, 1);
  __syncthreads();

  for (int kt = 0; kt < NT; kt += 2) {
    const int sA = kt & 3, sB = (kt + 1) & 3;
    // prefetch tiles kt+2, kt+3 into the slots freed at the last barrier
    if (kt + 2 < NT) {
      stage((kt + 2) & 3, kt + 2);
      stage((kt + 3) & 3, kt + 3);
    }
    // two-tile pipeline: QK_A, QK_B fill the matrix pipe; softmax_A (VALU)
    // overlaps QK_B drain; softmax_B overlaps PV_A.
    f32x16 scA[2] = {}, scB[2] = {};
    qk(&KV[sA][0], scA);
    qk(&KV[sB][0], scB);
    bf16x8 vfA[2][4];
    vload(&KV[sA][4096], vfA);
    bf16x8 pfA[4];
    softmax_pack(scA, pfA);
    pv(vfA, pfA);
    bf16x8 vfB[2][4];
    vload(&KV[sB][4096], vfB);
    bf16x8 pfB[4];
    softmax_pack(scB, pfB);
    pv(vfB, pfB);
    __syncthreads();
  }

  // ---- epilogue: combine halves' lsum, normalize (all lane-local), store
  lsum += __shfl_xor(lsum, 32, 64);
  float inv = 1.0f / lsum;
  u16* orow = Xo + ((size_t)b_ * SEQ + qrow) * EMBED + h_ * DKD;
#pragma unroll
  for (int dc = 0; dc < 2; dc++)
#pragma unroll
    for (int k4 = 0; k4 < 4; k4++) {
      u32 w0 = cvtpk(acc[dc][4 * k4 + 0] * inv, acc[dc][4 * k4 + 1] * inv);
      u32 w1 = cvtpk(acc[dc][4 * k4 + 2] * inv, acc[dc][4 * k4 + 3] * inv);
      int d = dc * 32 + k4 * 8 + h * 4;
      uint2 pk; pk.x = w0; pk.y = w1;
      *(uint2*)(orow + d) = pk;
    }
}

extern "C" void kernel_launch(void* const* d_in, const int* in_sizes, int n_in,
                              void* d_out, int out_size, void* d_ws, size_t ws_size,
                              hipStream_t stream) {
  const float* q  = (const float*)d_in[0];
  const float* k  = (const float*)d_in[1];
  const float* v  = (const float*)d_in[2];
  const float* Wq = (const float*)d_in[3];
  const float* Wk = (const float*)d_in[4];
  const float* Wv = (const float*)d_in[5];
  const float* Wo = (const float*)d_in[6];

  char* ws = (char*)d_ws;
  const size_t SZ_X = (size_t)MROWS * EMBED * 2;   // 8 MiB
  const size_t SZ_W = (size_t)EMBED * EMBED * 2;   // 2 MiB
  u16* wqb  = (u16*)(ws + 3 * SZ_X);
  u16* wkb  = (u16*)(ws + 3 * SZ_X + SZ_W);
  u16* wvb  = (u16*)(ws + 3 * SZ_X + 2 * SZ_W);
  u16* wob  = (u16*)(ws + 3 * SZ_X + 3 * SZ_W);
  u16* Qh   = (u16*)(ws + 3 * SZ_X + 4 * SZ_W);
  u16* Kh   = (u16*)(ws + 4 * SZ_X + 4 * SZ_W);
  u16* Vt   = (u16*)(ws + 5 * SZ_X + 4 * SZ_W);
  u16* Xcat = (u16*)(ws + 6 * SZ_X + 4 * SZ_W);    // total 64 MiB

  cast_w<<<dim3(128, 4), 256, 0, stream>>>(Wq, Wk, Wv, Wo, wqb, wkb, wvb, wob);

  gemm_qkv<<<dim3(MROWS / 128, EMBED / 128, 3), 256, 0, stream>>>(
      q, k, v, wqb, wkb, wvb, Qh, Kh, Vt);

  attn_kernel<<<512, 256, 0, stream>>>(Qh, Kh, Vt, Xcat);

  gemm_out<<<dim3(MROWS / 64, EMBED / 128), 256, 0, stream>>>(Xcat, wob, (float*)d_out);
}